// Round 1
// baseline (486.601 us; speedup 1.0000x reference)
//
#include <hip/hip_runtime.h>

#define BB 256
#define NN 64
#define NNODES 16384   // BB*NN
#define ND 11
#define TGT 12

__device__ __forceinline__ void fma4(float4& a, float s, const float4 b) {
    a.x = fmaf(s, b.x, a.x); a.y = fmaf(s, b.y, a.y);
    a.z = fmaf(s, b.z, a.z); a.w = fmaf(s, b.w, a.w);
}
__device__ __forceinline__ float sig1(float v) { return 1.f / (1.f + __expf(-v)); }
__device__ __forceinline__ float4 sig4(float4 v) {
    return make_float4(sig1(v.x), sig1(v.y), sig1(v.z), sig1(v.w));
}

// -------- K1: deg + m_e (written into M cols 256..319). wave per node. --------
__global__ __launch_bounds__(256) void k_me_deg(const float* __restrict__ g,
                                                const float* __restrict__ e,
                                                float* __restrict__ M,
                                                int* __restrict__ degidx) {
    const int lane = threadIdx.x & 63;
    const int node = blockIdx.x * 4 + (threadIdx.x >> 6);
    const float gv = g[(size_t)node * 64 + lane];
    float deg = gv;
    #pragma unroll
    for (int m = 32; m >= 1; m >>= 1) deg += __shfl_xor(deg, m);
    if (lane == 0) {
        int di = (int)(deg + 0.5f);
        degidx[node] = (di < ND) ? di : -1;
    }
    const int wsub = lane >> 4;
    const int cg = lane & 15;
    const float4* e4 = reinterpret_cast<const float4*>(e) + (size_t)node * 1024;
    float4 acc = make_float4(0.f, 0.f, 0.f, 0.f);
    #pragma unroll 4
    for (int w0 = 0; w0 < 64; w0 += 4) {
        int w = w0 + wsub;
        float gw = __shfl(gv, w);
        float4 ev = e4[w * 16 + cg];
        fma4(acc, gw, ev);
    }
    acc.x += __shfl_xor(acc.x, 16); acc.y += __shfl_xor(acc.y, 16);
    acc.z += __shfl_xor(acc.z, 16); acc.w += __shfl_xor(acc.w, 16);
    acc.x += __shfl_xor(acc.x, 32); acc.y += __shfl_xor(acc.y, 32);
    acc.z += __shfl_xor(acc.z, 32); acc.w += __shfl_xor(acc.w, 32);
    if (lane < 16) {
        float4* Mo = reinterpret_cast<float4*>(M + (size_t)node * 320 + 256);
        Mo[cg] = acc;
    }
}

// -------- K1b: degree buckets (order within bucket is irrelevant) --------
__global__ __launch_bounds__(256) void k_build_lists(const int* __restrict__ degidx,
                                                     int* __restrict__ counts,
                                                     int* __restrict__ lists) {
    int node = blockIdx.x * 256 + threadIdx.x;
    int d = degidx[node];
    if (d >= 0) {
        int pos = atomicAdd(&counts[d], 1);
        lists[d * NNODES + pos] = node;
    }
}

// -------- K2a: m_h = g @ h per batch (written into M cols 0..255) --------
__global__ __launch_bounds__(256) void k_mh(const float* __restrict__ g,
                                            const float* __restrict__ h,
                                            float* __restrict__ M) {
    __shared__ float hs[NN * 256];   // 64 KB
    __shared__ float gs[NN * NN];    // 16 KB, natural [v][w]
    const int b = blockIdx.x;
    const int tid = threadIdx.x;
    {
        const float4* hg = reinterpret_cast<const float4*>(h + (size_t)b * NN * 256);
        float4* hd = reinterpret_cast<float4*>(hs);
        #pragma unroll
        for (int j = 0; j < 16; ++j) hd[j * 256 + tid] = hg[j * 256 + tid];
        const float4* gg = reinterpret_cast<const float4*>(g + (size_t)b * NN * NN);
        float4* gd = reinterpret_cast<float4*>(gs);
        #pragma unroll
        for (int j = 0; j < 4; ++j) gd[j * 256 + tid] = gg[j * 256 + tid];
    }
    __syncthreads();
    const int tc = tid & 63;   // cols tc*4 .. tc*4+3
    const int tr = tid >> 6;   // rows tr*16 .. +15
    float4 acc[16];
    #pragma unroll
    for (int i = 0; i < 16; ++i) acc[i] = make_float4(0.f, 0.f, 0.f, 0.f);
    for (int w = 0; w < 64; ++w) {
        float4 h4 = *reinterpret_cast<const float4*>(&hs[w * 256 + tc * 4]);
        #pragma unroll
        for (int i = 0; i < 16; ++i) {
            float gvv = gs[(tr * 16 + i) * 64 + w];   // wave-uniform -> broadcast
            fma4(acc[i], gvv, h4);
        }
    }
    #pragma unroll
    for (int i = 0; i < 16; ++i) {
        int v = tr * 16 + i;
        *reinterpret_cast<float4*>(&M[((size_t)b * 64 + v) * 320 + tc * 4]) = acc[i];
    }
}

// -------- K2b: grouped update GEMM: h_out[row] = sigmoid(M[row,0:320] @ W[d]) --------
__global__ __launch_bounds__(512) void k_update(const float* __restrict__ M,
                                                const float* __restrict__ W,
                                                const int* __restrict__ lists,
                                                const int* __restrict__ counts,
                                                float* __restrict__ hout) {
    const int d = blockIdx.y;
    const int cnt = counts[d];
    const int base = blockIdx.x * 64;
    if (base >= cnt) return;
    __shared__ float As[32][64];     // A^T: [k][m]
    __shared__ float Bs[32][256];
    __shared__ int rows[64];
    const int tid = threadIdx.x;
    if (tid < 64) {
        int i = base + tid;
        rows[tid] = (i < cnt) ? lists[d * NNODES + i] : -1;
    }
    __syncthreads();
    const int tc = tid & 31;    // cols tc*4 and 128+tc*4
    const int tr = tid >> 5;    // rows tr*4 .. +3
    const int lm = tid >> 3;    // A-load row 0..63
    const int lk = (tid & 7) * 4;
    const int bk = tid >> 6;    // 0..7
    const int bc = (tid & 63) * 4;
    const int arow = rows[lm];
    const float* Wd = W + (size_t)d * 320 * 256;
    float4 acc0[4], acc1[4];
    #pragma unroll
    for (int i = 0; i < 4; ++i) {
        acc0[i] = make_float4(0.f, 0.f, 0.f, 0.f);
        acc1[i] = make_float4(0.f, 0.f, 0.f, 0.f);
    }
    for (int k0 = 0; k0 < 320; k0 += 32) {
        float4 av = make_float4(0.f, 0.f, 0.f, 0.f);
        if (arow >= 0)
            av = *reinterpret_cast<const float4*>(&M[(size_t)arow * 320 + k0 + lk]);
        As[lk + 0][lm] = av.x; As[lk + 1][lm] = av.y;
        As[lk + 2][lm] = av.z; As[lk + 3][lm] = av.w;
        #pragma unroll
        for (int p = 0; p < 4; ++p) {
            int kb = bk + p * 8;
            *reinterpret_cast<float4*>(&Bs[kb][bc]) =
                *reinterpret_cast<const float4*>(&Wd[(size_t)(k0 + kb) * 256 + bc]);
        }
        __syncthreads();
        #pragma unroll
        for (int k = 0; k < 32; ++k) {
            float4 a  = *reinterpret_cast<const float4*>(&As[k][tr * 4]);
            float4 b0 = *reinterpret_cast<const float4*>(&Bs[k][tc * 4]);
            float4 b1 = *reinterpret_cast<const float4*>(&Bs[k][128 + tc * 4]);
            fma4(acc0[0], a.x, b0); fma4(acc0[1], a.y, b0);
            fma4(acc0[2], a.z, b0); fma4(acc0[3], a.w, b0);
            fma4(acc1[0], a.x, b1); fma4(acc1[1], a.y, b1);
            fma4(acc1[2], a.z, b1); fma4(acc1[3], a.w, b1);
        }
        __syncthreads();
    }
    #pragma unroll
    for (int i = 0; i < 4; ++i) {
        int r = rows[tr * 4 + i];
        if (r >= 0) {
            float4 o0 = sig4(acc0[i]);
            float4 o1 = sig4(acc1[i]);
            *reinterpret_cast<float4*>(&hout[(size_t)r * 256 + tc * 4]) = o0;
            *reinterpret_cast<float4*>(&hout[(size_t)r * 256 + 128 + tc * 4]) = o1;
        }
    }
}

// -------- K3: readout GEMM (64 rows x 512 cols, K=256) + softmax + mask + batch-reduce --------
__global__ __launch_bounds__(512) void k_readout(const float* __restrict__ h0,
                                                 const float* __restrict__ h1,
                                                 const float* __restrict__ h2,
                                                 const float* __restrict__ R,
                                                 float* __restrict__ acc3) {
    const int b = blockIdx.x;
    const int layer = blockIdx.y;
    const float* h = (layer == 0) ? h0 : ((layer == 1) ? h1 : h2);
    const float* Rl = R + (size_t)layer * 256 * 512;
    __shared__ float As[32][64];
    __shared__ float Bs[32][512];    // 64 KB (re-used as reduction scratch)
    const int tid = threadIdx.x;
    const int tc = tid & 31;   // 16 cols: {c*128 + tc*4 | c=0..3}
    const int tr = tid >> 5;   // rows tr*4 .. +3
    const int lm = tid >> 3;
    const int lk = (tid & 7) * 4;
    const int bk = tid >> 6;
    const int bc = (tid & 63) * 8;
    float4 acc[4][4];
    #pragma unroll
    for (int i = 0; i < 4; ++i)
        #pragma unroll
        for (int c = 0; c < 4; ++c) acc[i][c] = make_float4(0.f, 0.f, 0.f, 0.f);
    const float* hrow = h + ((size_t)b * 64 + lm) * 256;
    for (int k0 = 0; k0 < 256; k0 += 32) {
        float4 av = *reinterpret_cast<const float4*>(&hrow[k0 + lk]);
        As[lk + 0][lm] = av.x; As[lk + 1][lm] = av.y;
        As[lk + 2][lm] = av.z; As[lk + 3][lm] = av.w;
        #pragma unroll
        for (int p = 0; p < 4; ++p) {
            int kb = bk + p * 8;
            const float4* src = reinterpret_cast<const float4*>(&Rl[(size_t)(k0 + kb) * 512 + bc]);
            float4* dst = reinterpret_cast<float4*>(&Bs[kb][bc]);
            dst[0] = src[0]; dst[1] = src[1];
        }
        __syncthreads();
        #pragma unroll
        for (int k = 0; k < 32; ++k) {
            float4 a = *reinterpret_cast<const float4*>(&As[k][tr * 4]);
            #pragma unroll
            for (int c = 0; c < 4; ++c) {
                float4 bv = *reinterpret_cast<const float4*>(&Bs[k][c * 128 + tc * 4]);
                fma4(acc[0][c], a.x, bv);
                fma4(acc[1][c], a.y, bv);
                fma4(acc[2][c], a.z, bv);
                fma4(acc[3][c], a.w, bv);
            }
        }
        __syncthreads();
    }
    // per-row masked softmax; accumulate this thread's 4 rows into cs
    float4 cs[4];
    #pragma unroll
    for (int c = 0; c < 4; ++c) cs[c] = make_float4(0.f, 0.f, 0.f, 0.f);
    #pragma unroll
    for (int i = 0; i < 4; ++i) {
        float mx = -3.4e38f, ma = 0.f;
        #pragma unroll
        for (int c = 0; c < 4; ++c) {
            float4 v = acc[i][c];
            mx = fmaxf(mx, fmaxf(fmaxf(v.x, v.y), fmaxf(v.z, v.w)));
            ma = fmaxf(ma, fmaxf(fmaxf(fabsf(v.x), fabsf(v.y)), fmaxf(fabsf(v.z), fabsf(v.w))));
        }
        #pragma unroll
        for (int m = 1; m <= 16; m <<= 1) {
            mx = fmaxf(mx, __shfl_xor(mx, m));
            ma = fmaxf(ma, __shfl_xor(ma, m));
        }
        if (ma > 0.f) {   // mask: any(z != 0); row-uniform across the 32 lanes
            float s = 0.f;
            #pragma unroll
            for (int c = 0; c < 4; ++c) {
                acc[i][c].x = __expf(acc[i][c].x - mx); s += acc[i][c].x;
                acc[i][c].y = __expf(acc[i][c].y - mx); s += acc[i][c].y;
                acc[i][c].z = __expf(acc[i][c].z - mx); s += acc[i][c].z;
                acc[i][c].w = __expf(acc[i][c].w - mx); s += acc[i][c].w;
            }
            #pragma unroll
            for (int m = 1; m <= 16; m <<= 1) s += __shfl_xor(s, m);
            float inv = 1.f / s;
            #pragma unroll
            for (int c = 0; c < 4; ++c) fma4(cs[c], inv, acc[i][c]);
        }
    }
    // block-level reduce of the 16 tr-groups -> acc3[layer][b][512]
    float* red = &Bs[0][0];
    #pragma unroll
    for (int c = 0; c < 4; ++c)
        *reinterpret_cast<float4*>(&red[(size_t)tr * 512 + c * 128 + tc * 4]) = cs[c];
    __syncthreads();
    float s = 0.f;
    #pragma unroll
    for (int t = 0; t < 16; ++t) s += red[t * 512 + tid];
    acc3[((size_t)layer * BB + b) * 512 + tid] = s;
}

// -------- K4: per-graph MLP head --------
__global__ __launch_bounds__(128) void k_mlp(const float* __restrict__ acc3,
                                             const float* __restrict__ fc0w, const float* __restrict__ fc0b,
                                             const float* __restrict__ fc1w, const float* __restrict__ fc1b,
                                             const float* __restrict__ fc2w, const float* __restrict__ fc2b,
                                             const float* __restrict__ fc3w, const float* __restrict__ fc3b,
                                             float* __restrict__ out) {
    const int b = blockIdx.x;
    const int tid = threadIdx.x;
    __shared__ float x0[512], x1[128], x2[256], x3[128];
    #pragma unroll
    for (int j = 0; j < 4; ++j) {
        int i = j * 128 + tid;
        x0[i] = acc3[(size_t)b * 512 + i]
              + acc3[((size_t)BB + b) * 512 + i]
              + acc3[((size_t)2 * BB + b) * 512 + i];
    }
    __syncthreads();
    {
        float a = fc0b[tid];
        for (int i = 0; i < 512; ++i) a = fmaf(x0[i], fc0w[i * 128 + tid], a);
        x1[tid] = fmaxf(a, 0.f);
    }
    __syncthreads();
    #pragma unroll
    for (int oo = 0; oo < 2; ++oo) {
        int o = oo * 128 + tid;
        float a = fc1b[o];
        for (int i = 0; i < 128; ++i) a = fmaf(x1[i], fc1w[i * 256 + o], a);
        x2[o] = fmaxf(a, 0.f);
    }
    __syncthreads();
    {
        float a = fc2b[tid];
        for (int i = 0; i < 256; ++i) a = fmaf(x2[i], fc2w[i * 128 + tid], a);
        x3[tid] = fmaxf(a, 0.f);
    }
    __syncthreads();
    if (tid < TGT) {
        float a = fc3b[tid];
        for (int i = 0; i < 128; ++i) a = fmaf(x3[i], fc3w[i * TGT + tid], a);
        out[(size_t)b * TGT + tid] = a;
    }
}

extern "C" void kernel_launch(void* const* d_in, const int* in_sizes, int n_in,
                              void* d_out, int out_size, void* d_ws, size_t ws_size,
                              hipStream_t stream) {
    (void)in_sizes; (void)n_in; (void)out_size; (void)ws_size;
    const float* g    = (const float*)d_in[0];
    const float* h_in = (const float*)d_in[1];
    const float* e    = (const float*)d_in[2];
    const float* Wu0  = (const float*)d_in[3];
    const float* Wu1  = (const float*)d_in[4];
    const float* R    = (const float*)d_in[5];
    const float* fc0w = (const float*)d_in[6];
    const float* fc0b = (const float*)d_in[7];
    const float* fc1w = (const float*)d_in[8];
    const float* fc1b = (const float*)d_in[9];
    const float* fc2w = (const float*)d_in[10];
    const float* fc2b = (const float*)d_in[11];
    const float* fc3w = (const float*)d_in[12];
    const float* fc3b = (const float*)d_in[13];
    float* out = (float*)d_out;

    char* p = (char*)d_ws;
    float* M    = (float*)p; p += (size_t)NNODES * 320 * 4;   // 20 MB  [node][320] = [m_h | m_e]
    int* degidx = (int*)p;   p += (size_t)NNODES * 4;
    int* counts = (int*)p;   p += 256;
    int* lists  = (int*)p;   p += (size_t)ND * NNODES * 4;
    float* h1   = (float*)p; p += (size_t)NNODES * 256 * 4;   // 16 MB
    float* h2   = (float*)p; p += (size_t)NNODES * 256 * 4;   // 16 MB
    float* acc3 = (float*)p; p += (size_t)3 * BB * 512 * 4;

    hipMemsetAsync(counts, 0, 256, stream);
    hipMemsetAsync(h1, 0, (size_t)NNODES * 256 * 4, stream);   // invalid-degree rows stay 0
    hipMemsetAsync(h2, 0, (size_t)NNODES * 256 * 4, stream);

    k_me_deg<<<NNODES / 4, 256, 0, stream>>>(g, e, M, degidx);
    k_build_lists<<<NNODES / 256, 256, 0, stream>>>(degidx, counts, lists);

    k_mh<<<BB, 256, 0, stream>>>(g, h_in, M);
    k_update<<<dim3(256, ND), 512, 0, stream>>>(M, Wu0, lists, counts, h1);

    k_mh<<<BB, 256, 0, stream>>>(g, h1, M);
    k_update<<<dim3(256, ND), 512, 0, stream>>>(M, Wu1, lists, counts, h2);

    k_readout<<<dim3(BB, 3), 512, 0, stream>>>(h_in, h1, h2, R, acc3);

    k_mlp<<<BB, 128, 0, stream>>>(acc3, fc0w, fc0b, fc1w, fc1b, fc2w, fc2b, fc3w, fc3b, out);
}

// Round 2
// 400.109 us; speedup vs baseline: 1.2162x; 1.2162x over previous
//
#include <hip/hip_runtime.h>
#include <hip/hip_bf16.h>

#define BB 256
#define NN 64
#define NNODES 16384   // BB*NN
#define ND 11
#define TGT 12

typedef __attribute__((ext_vector_type(8))) short s16x8;
typedef __attribute__((ext_vector_type(4))) float f32x4;

__device__ __forceinline__ void fma4(float4& a, float s, const float4 b) {
    a.x = fmaf(s, b.x, a.x); a.y = fmaf(s, b.y, a.y);
    a.z = fmaf(s, b.z, a.z); a.w = fmaf(s, b.w, a.w);
}
__device__ __forceinline__ float sig1(float v) { return 1.f / (1.f + __expf(-v)); }
__device__ __forceinline__ float4 sig4(float4 v) {
    return make_float4(sig1(v.x), sig1(v.y), sig1(v.z), sig1(v.w));
}
__device__ __forceinline__ float bf2f(unsigned short u) {
    union { unsigned int i; float f; } v; v.i = ((unsigned int)u) << 16; return v.f;
}
__device__ __forceinline__ unsigned short f2bf(float f) {
    __hip_bfloat16 b = __float2bfloat16(f);   // RNE
    return *reinterpret_cast<unsigned short*>(&b);
}

// -------- K1: deg + m_e (written into M cols 256..319). wave per node. --------
__global__ __launch_bounds__(256) void k_me_deg(const float* __restrict__ g,
                                                const float* __restrict__ e,
                                                float* __restrict__ M,
                                                int* __restrict__ degidx) {
    const int lane = threadIdx.x & 63;
    const int node = blockIdx.x * 4 + (threadIdx.x >> 6);
    const float gv = g[(size_t)node * 64 + lane];
    float deg = gv;
    #pragma unroll
    for (int m = 32; m >= 1; m >>= 1) deg += __shfl_xor(deg, m);
    if (lane == 0) {
        int di = (int)(deg + 0.5f);
        degidx[node] = (di < ND) ? di : -1;
    }
    const int wsub = lane >> 4;
    const int cg = lane & 15;
    const float4* e4 = reinterpret_cast<const float4*>(e) + (size_t)node * 1024;
    float4 acc = make_float4(0.f, 0.f, 0.f, 0.f);
    #pragma unroll 4
    for (int w0 = 0; w0 < 64; w0 += 4) {
        int w = w0 + wsub;
        float gw = __shfl(gv, w);
        float4 ev = e4[w * 16 + cg];
        fma4(acc, gw, ev);
    }
    acc.x += __shfl_xor(acc.x, 16); acc.y += __shfl_xor(acc.y, 16);
    acc.z += __shfl_xor(acc.z, 16); acc.w += __shfl_xor(acc.w, 16);
    acc.x += __shfl_xor(acc.x, 32); acc.y += __shfl_xor(acc.y, 32);
    acc.z += __shfl_xor(acc.z, 32); acc.w += __shfl_xor(acc.w, 32);
    if (lane < 16) {
        float4* Mo = reinterpret_cast<float4*>(M + (size_t)node * 320 + 256);
        Mo[cg] = acc;
    }
}

// -------- K1b: degree buckets --------
__global__ __launch_bounds__(256) void k_build_lists(const int* __restrict__ degidx,
                                                     int* __restrict__ counts,
                                                     int* __restrict__ lists) {
    int node = blockIdx.x * 256 + threadIdx.x;
    int d = degidx[node];
    if (d >= 0) {
        int pos = atomicAdd(&counts[d], 1);
        lists[d * NNODES + pos] = node;
    }
}

// -------- conversions --------
__global__ __launch_bounds__(256) void k_cvt_h(const float* __restrict__ h,
                                               unsigned short* __restrict__ hb) {
    int i = blockIdx.x * 256 + threadIdx.x;
    float4 v = reinterpret_cast<const float4*>(h)[i];
    ushort4 u = make_ushort4(f2bf(v.x), f2bf(v.y), f2bf(v.z), f2bf(v.w));
    reinterpret_cast<ushort4*>(hb)[i] = u;
}

// R [3][256][512] f32 -> Rt [3][512][256] bf16
__global__ __launch_bounds__(256) void k_cvt_R(const float* __restrict__ R,
                                               unsigned short* __restrict__ Rt) {
    __shared__ float st[64][65];
    const int l = blockIdx.y;
    const int kt = (blockIdx.x & 3) * 64;
    const int nt = (blockIdx.x >> 2) * 64;
    const int tx = threadIdx.x & 63, ty = threadIdx.x >> 6;   // ty 0..3
    const float* Rl = R + (size_t)l * 256 * 512;
    #pragma unroll
    for (int j = 0; j < 16; ++j) {
        int kl = ty + j * 4;
        st[kl][tx] = Rl[(size_t)(kt + kl) * 512 + nt + tx];
    }
    __syncthreads();
    unsigned short* RtL = Rt + (size_t)l * 512 * 256;
    #pragma unroll
    for (int j = 0; j < 16; ++j) {
        int nl = ty + j * 4;
        RtL[(size_t)(nt + nl) * 256 + kt + tx] = f2bf(st[tx][nl]);
    }
}

// -------- K2a: m_h = g @ h per batch (written into M cols 0..255) --------
template<bool BF>
__global__ __launch_bounds__(256) void k_mh(const float* __restrict__ g,
                                            const void* __restrict__ hp,
                                            float* __restrict__ M) {
    __shared__ float hs[NN * 256];   // 64 KB
    __shared__ float gs[NN * NN];    // 16 KB
    const int b = blockIdx.x;
    const int tid = threadIdx.x;
    {
        float4* hd = reinterpret_cast<float4*>(hs);
        if (BF) {
            const ushort4* hg = reinterpret_cast<const ushort4*>(
                (const unsigned short*)hp + (size_t)b * NN * 256);
            #pragma unroll
            for (int j = 0; j < 16; ++j) {
                ushort4 u = hg[j * 256 + tid];
                hd[j * 256 + tid] = make_float4(bf2f(u.x), bf2f(u.y), bf2f(u.z), bf2f(u.w));
            }
        } else {
            const float4* hg = reinterpret_cast<const float4*>(
                (const float*)hp + (size_t)b * NN * 256);
            #pragma unroll
            for (int j = 0; j < 16; ++j) hd[j * 256 + tid] = hg[j * 256 + tid];
        }
        const float4* gg = reinterpret_cast<const float4*>(g + (size_t)b * NN * NN);
        float4* gd = reinterpret_cast<float4*>(gs);
        #pragma unroll
        for (int j = 0; j < 4; ++j) gd[j * 256 + tid] = gg[j * 256 + tid];
    }
    __syncthreads();
    const int tc = tid & 63;
    const int tr = tid >> 6;
    float4 acc[16];
    #pragma unroll
    for (int i = 0; i < 16; ++i) acc[i] = make_float4(0.f, 0.f, 0.f, 0.f);
    for (int w = 0; w < 64; ++w) {
        float4 h4 = *reinterpret_cast<const float4*>(&hs[w * 256 + tc * 4]);
        #pragma unroll
        for (int i = 0; i < 16; ++i) {
            float gvv = gs[(tr * 16 + i) * 64 + w];
            fma4(acc[i], gvv, h4);
        }
    }
    #pragma unroll
    for (int i = 0; i < 16; ++i) {
        int v = tr * 16 + i;
        *reinterpret_cast<float4*>(&M[((size_t)b * 64 + v) * 320 + tc * 4]) = acc[i];
    }
}

// -------- K2b: grouped update GEMM -> bf16 h_out --------
__global__ __launch_bounds__(512) void k_update(const float* __restrict__ M,
                                                const float* __restrict__ W,
                                                const int* __restrict__ lists,
                                                const int* __restrict__ counts,
                                                unsigned short* __restrict__ houtb) {
    const int d = blockIdx.y;
    const int cnt = counts[d];
    const int base = blockIdx.x * 64;
    if (base >= cnt) return;
    __shared__ float As[32][64];
    __shared__ float Bs[32][256];
    __shared__ int rows[64];
    const int tid = threadIdx.x;
    if (tid < 64) {
        int i = base + tid;
        rows[tid] = (i < cnt) ? lists[d * NNODES + i] : -1;
    }
    __syncthreads();
    const int tc = tid & 31;
    const int tr = tid >> 5;
    const int lm = tid >> 3;
    const int lk = (tid & 7) * 4;
    const int bk = tid >> 6;
    const int bc = (tid & 63) * 4;
    const int arow = rows[lm];
    const float* Wd = W + (size_t)d * 320 * 256;
    float4 acc0[4], acc1[4];
    #pragma unroll
    for (int i = 0; i < 4; ++i) {
        acc0[i] = make_float4(0.f, 0.f, 0.f, 0.f);
        acc1[i] = make_float4(0.f, 0.f, 0.f, 0.f);
    }
    for (int k0 = 0; k0 < 320; k0 += 32) {
        float4 av = make_float4(0.f, 0.f, 0.f, 0.f);
        if (arow >= 0)
            av = *reinterpret_cast<const float4*>(&M[(size_t)arow * 320 + k0 + lk]);
        As[lk + 0][lm] = av.x; As[lk + 1][lm] = av.y;
        As[lk + 2][lm] = av.z; As[lk + 3][lm] = av.w;
        #pragma unroll
        for (int p = 0; p < 4; ++p) {
            int kb = bk + p * 8;
            *reinterpret_cast<float4*>(&Bs[kb][bc]) =
                *reinterpret_cast<const float4*>(&Wd[(size_t)(k0 + kb) * 256 + bc]);
        }
        __syncthreads();
        #pragma unroll
        for (int k = 0; k < 32; ++k) {
            float4 a  = *reinterpret_cast<const float4*>(&As[k][tr * 4]);
            float4 b0 = *reinterpret_cast<const float4*>(&Bs[k][tc * 4]);
            float4 b1 = *reinterpret_cast<const float4*>(&Bs[k][128 + tc * 4]);
            fma4(acc0[0], a.x, b0); fma4(acc0[1], a.y, b0);
            fma4(acc0[2], a.z, b0); fma4(acc0[3], a.w, b0);
            fma4(acc1[0], a.x, b1); fma4(acc1[1], a.y, b1);
            fma4(acc1[2], a.z, b1); fma4(acc1[3], a.w, b1);
        }
        __syncthreads();
    }
    #pragma unroll
    for (int i = 0; i < 4; ++i) {
        int r = rows[tr * 4 + i];
        if (r >= 0) {
            float4 o0 = sig4(acc0[i]);
            float4 o1 = sig4(acc1[i]);
            ushort4 u0 = make_ushort4(f2bf(o0.x), f2bf(o0.y), f2bf(o0.z), f2bf(o0.w));
            ushort4 u1 = make_ushort4(f2bf(o1.x), f2bf(o1.y), f2bf(o1.z), f2bf(o1.w));
            *reinterpret_cast<ushort4*>(&houtb[(size_t)r * 256 + tc * 4]) = u0;
            *reinterpret_cast<ushort4*>(&houtb[(size_t)r * 256 + 128 + tc * 4]) = u1;
        }
    }
}

// -------- K3: MFMA readout: C = h(64x256) @ R(256x512), softmax, mask, row-sum --------
// 4 waves; wave w owns rows w*16..w*16+15, all 512 cols. B^T (Rt) streamed in
// 32-col chunks through XOR-swizzled LDS. mfma_f32_16x16x32_bf16.
__global__ __launch_bounds__(256) void k_readout_mfma(
        const unsigned short* __restrict__ hb0,
        const unsigned short* __restrict__ hb1,
        const unsigned short* __restrict__ hb2,
        const unsigned short* __restrict__ Rt,   // [3][512][256] bf16
        float* __restrict__ acc3) {
    const int b = blockIdx.x, layer = blockIdx.y;
    const unsigned short* hb = (layer == 0) ? hb0 : ((layer == 1) ? hb1 : hb2);
    const unsigned short* RtL = Rt + (size_t)layer * 512 * 256;
    __shared__ __align__(16) unsigned short Ab[64 * 256];   // 32 KB, swizzled
    __shared__ __align__(16) unsigned short Bst[32 * 256];  // 16 KB, swizzled
    __shared__ float red[4 * 512];                          // 8 KB
    const int tid = threadIdx.x;
    const int w = tid >> 6, lane = tid & 63;

    // stage A: row r = tid>>2, 8 chunks of 16B, contiguous 64B groups, swizzled
    {
        const int r = tid >> 2;
        const uint4* src = reinterpret_cast<const uint4*>(hb + ((size_t)(b * 64 + r)) * 256);
        #pragma unroll
        for (int j = 0; j < 8; ++j) {
            int c = (tid & 3) + j * 4;
            uint4 v = src[c];
            *reinterpret_cast<uint4*>(&Ab[r * 256 + (c ^ (r & 7)) * 8]) = v;
        }
    }
    __syncthreads();

    // preload A fragments: lane holds A[ar][ks*32 + (lane>>4)*8 + j]
    const int ar = w * 16 + (lane & 15);
    s16x8 af[8];
    #pragma unroll
    for (int ks = 0; ks < 8; ++ks) {
        int c = (lane >> 4) + ks * 4;
        af[ks] = *reinterpret_cast<const s16x8*>(&Ab[ar * 256 + (c ^ (ar & 7)) * 8]);
    }

    f32x4 acc[32];
    #pragma unroll
    for (int nt = 0; nt < 32; ++nt) acc[nt] = (f32x4){0.f, 0.f, 0.f, 0.f};

    #pragma unroll
    for (int it = 0; it < 16; ++it) {
        __syncthreads();   // previous iter's readers done
        {
            const int nl = tid >> 3;
            const uint4* src = reinterpret_cast<const uint4*>(RtL + ((size_t)(it * 32 + nl)) * 256);
            #pragma unroll
            for (int j = 0; j < 4; ++j) {
                int c = (tid & 7) + j * 8;
                uint4 v = src[c];
                *reinterpret_cast<uint4*>(&Bst[nl * 256 + (c ^ (nl & 7)) * 8]) = v;
            }
        }
        __syncthreads();
        #pragma unroll
        for (int hh = 0; hh < 2; ++hh) {
            const int nl = hh * 16 + (lane & 15);
            const int swz = nl & 7;
            f32x4 a = acc[it * 2 + hh];
            #pragma unroll
            for (int ks = 0; ks < 8; ++ks) {
                int c = (lane >> 4) + ks * 4;
                s16x8 bf = *reinterpret_cast<const s16x8*>(&Bst[nl * 256 + (c ^ swz) * 8]);
                a = __builtin_amdgcn_mfma_f32_16x16x32_bf16(af[ks], bf, a, 0, 0, 0);
            }
            acc[it * 2 + hh] = a;
        }
    }

    // per-row masked softmax + node-sum. Row of reg r: (lane>>4)*4 + r; col: nt*16 + (lane&15).
    float colacc[32];
    #pragma unroll
    for (int nt = 0; nt < 32; ++nt) colacc[nt] = 0.f;
    #pragma unroll
    for (int r = 0; r < 4; ++r) {
        float mx = -3.4e38f, ma = 0.f;
        #pragma unroll
        for (int nt = 0; nt < 32; ++nt) {
            float v = acc[nt][r];
            mx = fmaxf(mx, v);
            ma = fmaxf(ma, fabsf(v));
        }
        #pragma unroll
        for (int m = 1; m <= 8; m <<= 1) {
            mx = fmaxf(mx, __shfl_xor(mx, m));
            ma = fmaxf(ma, __shfl_xor(ma, m));
        }
        if (ma > 0.f) {   // mask: row has any nonzero (uniform in 16-lane group)
            float s = 0.f;
            float p[32];
            #pragma unroll
            for (int nt = 0; nt < 32; ++nt) { p[nt] = __expf(acc[nt][r] - mx); s += p[nt]; }
            #pragma unroll
            for (int m = 1; m <= 8; m <<= 1) s += __shfl_xor(s, m);
            float inv = 1.f / s;
            #pragma unroll
            for (int nt = 0; nt < 32; ++nt) colacc[nt] = fmaf(p[nt], inv, colacc[nt]);
        }
    }
    // sum the 4 row-groups of this wave
    #pragma unroll
    for (int nt = 0; nt < 32; ++nt) {
        float v = colacc[nt];
        v += __shfl_xor(v, 16);
        v += __shfl_xor(v, 32);
        colacc[nt] = v;
    }
    if (lane < 16) {
        #pragma unroll
        for (int nt = 0; nt < 32; ++nt) red[w * 512 + nt * 16 + lane] = colacc[nt];
    }
    __syncthreads();
    float* o = acc3 + ((size_t)layer * BB + b) * 512;
    #pragma unroll
    for (int part = 0; part < 2; ++part) {
        int idx = part * 256 + tid;
        o[idx] = red[idx] + red[512 + idx] + red[1024 + idx] + red[1536 + idx];
    }
}

// -------- K4: per-graph MLP head --------
__global__ __launch_bounds__(128) void k_mlp(const float* __restrict__ acc3,
                                             const float* __restrict__ fc0w, const float* __restrict__ fc0b,
                                             const float* __restrict__ fc1w, const float* __restrict__ fc1b,
                                             const float* __restrict__ fc2w, const float* __restrict__ fc2b,
                                             const float* __restrict__ fc3w, const float* __restrict__ fc3b,
                                             float* __restrict__ out) {
    const int b = blockIdx.x;
    const int tid = threadIdx.x;
    __shared__ float x0[512], x1[128], x2[256], x3[128];
    #pragma unroll
    for (int j = 0; j < 4; ++j) {
        int i = j * 128 + tid;
        x0[i] = acc3[(size_t)b * 512 + i]
              + acc3[((size_t)BB + b) * 512 + i]
              + acc3[((size_t)2 * BB + b) * 512 + i];
    }
    __syncthreads();
    {
        float a = fc0b[tid];
        for (int i = 0; i < 512; ++i) a = fmaf(x0[i], fc0w[i * 128 + tid], a);
        x1[tid] = fmaxf(a, 0.f);
    }
    __syncthreads();
    #pragma unroll
    for (int oo = 0; oo < 2; ++oo) {
        int o = oo * 128 + tid;
        float a = fc1b[o];
        for (int i = 0; i < 128; ++i) a = fmaf(x1[i], fc1w[i * 256 + o], a);
        x2[o] = fmaxf(a, 0.f);
    }
    __syncthreads();
    {
        float a = fc2b[tid];
        for (int i = 0; i < 256; ++i) a = fmaf(x2[i], fc2w[i * 128 + tid], a);
        x3[tid] = fmaxf(a, 0.f);
    }
    __syncthreads();
    if (tid < TGT) {
        float a = fc3b[tid];
        for (int i = 0; i < 128; ++i) a = fmaf(x3[i], fc3w[i * TGT + tid], a);
        out[(size_t)b * TGT + tid] = a;
    }
}

extern "C" void kernel_launch(void* const* d_in, const int* in_sizes, int n_in,
                              void* d_out, int out_size, void* d_ws, size_t ws_size,
                              hipStream_t stream) {
    (void)in_sizes; (void)n_in; (void)out_size; (void)ws_size;
    const float* g    = (const float*)d_in[0];
    const float* h_in = (const float*)d_in[1];
    const float* e    = (const float*)d_in[2];
    const float* Wu0  = (const float*)d_in[3];
    const float* Wu1  = (const float*)d_in[4];
    const float* R    = (const float*)d_in[5];
    const float* fc0w = (const float*)d_in[6];
    const float* fc0b = (const float*)d_in[7];
    const float* fc1w = (const float*)d_in[8];
    const float* fc1b = (const float*)d_in[9];
    const float* fc2w = (const float*)d_in[10];
    const float* fc2b = (const float*)d_in[11];
    const float* fc3w = (const float*)d_in[12];
    const float* fc3b = (const float*)d_in[13];
    float* out = (float*)d_out;

    char* p = (char*)d_ws;
    float* M    = (float*)p;          p += (size_t)NNODES * 320 * 4;   // 20 MB
    unsigned short* hb0 = (unsigned short*)p; p += (size_t)NNODES * 256 * 2;  // 8 MB
    unsigned short* hb1 = (unsigned short*)p; p += (size_t)NNODES * 256 * 2;  // 8 MB
    unsigned short* hb2 = (unsigned short*)p; p += (size_t)NNODES * 256 * 2;  // 8 MB
    unsigned short* Rt  = (unsigned short*)p; p += (size_t)3 * 512 * 256 * 2; // 0.75 MB
    float* acc3 = (float*)p;          p += (size_t)3 * BB * 512 * 4;   // 1.5 MB
    int* degidx = (int*)p;            p += (size_t)NNODES * 4;
    int* counts = (int*)p;            p += 256;
    int* lists  = (int*)p;            p += (size_t)ND * NNODES * 4;

    hipMemsetAsync(counts, 0, 256, stream);
    hipMemsetAsync(hb1, 0, (size_t)NNODES * 256 * 2, stream);  // invalid-degree rows stay 0
    hipMemsetAsync(hb2, 0, (size_t)NNODES * 256 * 2, stream);

    k_me_deg<<<NNODES / 4, 256, 0, stream>>>(g, e, M, degidx);
    k_build_lists<<<NNODES / 256, 256, 0, stream>>>(degidx, counts, lists);
    k_cvt_h<<<NNODES * 256 / 4 / 256, 256, 0, stream>>>(h_in, hb0);
    k_cvt_R<<<dim3(32, 3), 256, 0, stream>>>(R, Rt);

    k_mh<false><<<BB, 256, 0, stream>>>(g, h_in, M);
    k_update<<<dim3(256, ND), 512, 0, stream>>>(M, Wu0, lists, counts, hb1);

    k_mh<true><<<BB, 256, 0, stream>>>(g, hb1, M);
    k_update<<<dim3(256, ND), 512, 0, stream>>>(M, Wu1, lists, counts, hb2);

    k_readout_mfma<<<dim3(BB, 3), 256, 0, stream>>>(hb0, hb1, hb2, Rt, acc3);

    k_mlp<<<BB, 128, 0, stream>>>(acc3, fc0w, fc0b, fc1w, fc1b, fc2w, fc2b, fc3w, fc3b, out);
}

// Round 3
// 301.120 us; speedup vs baseline: 1.6160x; 1.3287x over previous
//
#include <hip/hip_runtime.h>
#include <hip/hip_bf16.h>

#define BB 256
#define NN 64
#define NNODES 16384   // BB*NN
#define ND 11
#define TGT 12

typedef __attribute__((ext_vector_type(8))) short s16x8;
typedef __attribute__((ext_vector_type(4))) float f32x4;

__device__ __forceinline__ void fma4(float4& a, float s, const float4 b) {
    a.x = fmaf(s, b.x, a.x); a.y = fmaf(s, b.y, a.y);
    a.z = fmaf(s, b.z, a.z); a.w = fmaf(s, b.w, a.w);
}
__device__ __forceinline__ float sig1(float v) { return 1.f / (1.f + __expf(-v)); }
__device__ __forceinline__ float bf2f(unsigned short u) {
    union { unsigned int i; float f; } v; v.i = ((unsigned int)u) << 16; return v.f;
}
__device__ __forceinline__ unsigned short f2bf(float f) {
    __hip_bfloat16 b = __float2bfloat16(f);   // RNE
    return *reinterpret_cast<unsigned short*>(&b);
}

// -------- K1: deg + m_e -> Mb cols 256..319 (bf16). wave per node. Zeros counts. --------
__global__ __launch_bounds__(256) void k_me_deg(const float* __restrict__ g,
                                                const float* __restrict__ e,
                                                unsigned short* __restrict__ Mb,
                                                int* __restrict__ degidx,
                                                int* __restrict__ counts) {
    if (blockIdx.x == 0 && threadIdx.x < 16) counts[threadIdx.x] = 0;
    const int lane = threadIdx.x & 63;
    const int node = blockIdx.x * 4 + (threadIdx.x >> 6);
    const float gv = g[(size_t)node * 64 + lane];
    float deg = gv;
    #pragma unroll
    for (int m = 32; m >= 1; m >>= 1) deg += __shfl_xor(deg, m);
    if (lane == 0) {
        int di = (int)(deg + 0.5f);
        degidx[node] = (di < ND) ? di : -1;
    }
    const int wsub = lane >> 4;
    const int cg = lane & 15;
    const float4* e4 = reinterpret_cast<const float4*>(e) + (size_t)node * 1024;
    float4 acc = make_float4(0.f, 0.f, 0.f, 0.f);
    #pragma unroll 4
    for (int w0 = 0; w0 < 64; w0 += 4) {
        int w = w0 + wsub;
        float gw = __shfl(gv, w);
        float4 ev = e4[w * 16 + cg];
        fma4(acc, gw, ev);
    }
    acc.x += __shfl_xor(acc.x, 16); acc.y += __shfl_xor(acc.y, 16);
    acc.z += __shfl_xor(acc.z, 16); acc.w += __shfl_xor(acc.w, 16);
    acc.x += __shfl_xor(acc.x, 32); acc.y += __shfl_xor(acc.y, 32);
    acc.z += __shfl_xor(acc.z, 32); acc.w += __shfl_xor(acc.w, 32);
    if (lane < 16) {
        ushort4 u = make_ushort4(f2bf(acc.x), f2bf(acc.y), f2bf(acc.z), f2bf(acc.w));
        *reinterpret_cast<ushort4*>(&Mb[(size_t)node * 320 + 256 + cg * 4]) = u;
    }
}

// -------- K1b: degree buckets + zero invalid-degree hb1/hb2 rows --------
__global__ __launch_bounds__(256) void k_build_lists(const int* __restrict__ degidx,
                                                     int* __restrict__ counts,
                                                     int* __restrict__ lists,
                                                     unsigned short* __restrict__ hb1,
                                                     unsigned short* __restrict__ hb2) {
    int node = blockIdx.x * 256 + threadIdx.x;
    int d = degidx[node];
    if (d >= 0) {
        int pos = atomicAdd(&counts[d], 1);
        lists[d * NNODES + pos] = node;
    } else {
        uint4 z = make_uint4(0, 0, 0, 0);
        uint4* p1 = reinterpret_cast<uint4*>(&hb1[(size_t)node * 256]);
        uint4* p2 = reinterpret_cast<uint4*>(&hb2[(size_t)node * 256]);
        #pragma unroll
        for (int j = 0; j < 32; ++j) { p1[j] = z; p2[j] = z; }
    }
}

// -------- conversions --------
__global__ __launch_bounds__(256) void k_cvt_h(const float* __restrict__ h,
                                               unsigned short* __restrict__ hb) {
    int i = blockIdx.x * 256 + threadIdx.x;
    float4 v = reinterpret_cast<const float4*>(h)[i];
    ushort4 u = make_ushort4(f2bf(v.x), f2bf(v.y), f2bf(v.z), f2bf(v.w));
    reinterpret_cast<ushort4*>(hb)[i] = u;
}

// R [3][256][512] f32 -> Rt [3][512][256] bf16
__global__ __launch_bounds__(256) void k_cvt_R(const float* __restrict__ R,
                                               unsigned short* __restrict__ Rt) {
    __shared__ float st[64][65];
    const int l = blockIdx.y;
    const int kt = (blockIdx.x & 3) * 64;
    const int nt = (blockIdx.x >> 2) * 64;
    const int tx = threadIdx.x & 63, ty = threadIdx.x >> 6;
    const float* Rl = R + (size_t)l * 256 * 512;
    #pragma unroll
    for (int j = 0; j < 16; ++j) {
        int kl = ty + j * 4;
        st[kl][tx] = Rl[(size_t)(kt + kl) * 512 + nt + tx];
    }
    __syncthreads();
    unsigned short* RtL = Rt + (size_t)l * 512 * 256;
    #pragma unroll
    for (int j = 0; j < 16; ++j) {
        int nl = ty + j * 4;
        RtL[(size_t)(nt + nl) * 256 + kt + tx] = f2bf(st[tx][nl]);
    }
}

// W [ND][320][256] f32 -> Wt [ND][256][320] bf16
__global__ __launch_bounds__(256) void k_cvt_W(const float* __restrict__ W,
                                               unsigned short* __restrict__ Wt) {
    __shared__ float st[64][65];
    const int d = blockIdx.y;
    const int kt = (blockIdx.x % 5) * 64;    // K tile (320)
    const int ct = (blockIdx.x / 5) * 64;    // col tile (256)
    const int tx = threadIdx.x & 63, ty = threadIdx.x >> 6;
    const float* Wd = W + (size_t)d * 320 * 256;
    #pragma unroll
    for (int j = 0; j < 16; ++j) {
        int kl = ty + j * 4;
        st[kl][tx] = Wd[(size_t)(kt + kl) * 256 + ct + tx];
    }
    __syncthreads();
    unsigned short* Wo = Wt + (size_t)d * 256 * 320;
    #pragma unroll
    for (int j = 0; j < 16; ++j) {
        int cl = ty + j * 4;
        Wo[(size_t)(ct + cl) * 320 + kt + tx] = f2bf(st[tx][cl]);
    }
}

// -------- K2a: m_h = g @ h per batch -> Mb cols 0..255 (bf16) --------
template<bool BF>
__global__ __launch_bounds__(256) void k_mh(const float* __restrict__ g,
                                            const void* __restrict__ hp,
                                            unsigned short* __restrict__ Mb) {
    __shared__ float hs[NN * 256];   // 64 KB
    __shared__ float gs[NN * NN];    // 16 KB
    const int b = blockIdx.x;
    const int tid = threadIdx.x;
    {
        float4* hd = reinterpret_cast<float4*>(hs);
        if (BF) {
            const ushort4* hg = reinterpret_cast<const ushort4*>(
                (const unsigned short*)hp + (size_t)b * NN * 256);
            #pragma unroll
            for (int j = 0; j < 16; ++j) {
                ushort4 u = hg[j * 256 + tid];
                hd[j * 256 + tid] = make_float4(bf2f(u.x), bf2f(u.y), bf2f(u.z), bf2f(u.w));
            }
        } else {
            const float4* hg = reinterpret_cast<const float4*>(
                (const float*)hp + (size_t)b * NN * 256);
            #pragma unroll
            for (int j = 0; j < 16; ++j) hd[j * 256 + tid] = hg[j * 256 + tid];
        }
        const float4* gg = reinterpret_cast<const float4*>(g + (size_t)b * NN * NN);
        float4* gd = reinterpret_cast<float4*>(gs);
        #pragma unroll
        for (int j = 0; j < 4; ++j) gd[j * 256 + tid] = gg[j * 256 + tid];
    }
    __syncthreads();
    const int tc = tid & 63;
    const int tr = tid >> 6;
    float4 acc[16];
    #pragma unroll
    for (int i = 0; i < 16; ++i) acc[i] = make_float4(0.f, 0.f, 0.f, 0.f);
    for (int w = 0; w < 64; ++w) {
        float4 h4 = *reinterpret_cast<const float4*>(&hs[w * 256 + tc * 4]);
        #pragma unroll
        for (int i = 0; i < 16; ++i) {
            float gvv = gs[(tr * 16 + i) * 64 + w];
            fma4(acc[i], gvv, h4);
        }
    }
    #pragma unroll
    for (int i = 0; i < 16; ++i) {
        int v = tr * 16 + i;
        ushort4 u = make_ushort4(f2bf(acc[i].x), f2bf(acc[i].y), f2bf(acc[i].z), f2bf(acc[i].w));
        *reinterpret_cast<ushort4*>(&Mb[((size_t)(b * 64 + v)) * 320 + tc * 4]) = u;
    }
}

// -------- K2b: grouped update via MFMA, LDS-free operand streaming --------
// Block: 64 gathered rows x 256 cols, K=320. 4 waves; wave w -> cols w*64..+63.
// A/B fragments loaded directly from global (L2-resident), 4x4 outer product.
__global__ __launch_bounds__(256) void k_update_mfma(
        const unsigned short* __restrict__ Mb,
        const unsigned short* __restrict__ Wt,
        const int* __restrict__ lists,
        const int* __restrict__ counts,
        unsigned short* __restrict__ houtb) {
    const int d = blockIdx.y;
    const int cnt = counts[d];
    const int base = blockIdx.x * 64;
    if (base >= cnt) return;
    __shared__ int rows[64];
    const int tid = threadIdx.x;
    if (tid < 64) {
        int i = base + tid;
        rows[tid] = (i < cnt) ? lists[d * NNODES + i] : -1;
    }
    __syncthreads();
    const int w = tid >> 6, lane = tid & 63;
    const int g = lane >> 4, c16 = lane & 15;
    const unsigned short* WtD = Wt + (size_t)d * 256 * 320;
    int arow[4];
    #pragma unroll
    for (int rt = 0; rt < 4; ++rt) {
        int r = rows[rt * 16 + c16];
        arow[rt] = (r < 0) ? 0 : r;   // clamped rows: real data, output discarded
    }
    f32x4 acc[4][4];
    #pragma unroll
    for (int rt = 0; rt < 4; ++rt)
        #pragma unroll
        for (int ct = 0; ct < 4; ++ct) acc[rt][ct] = (f32x4){0.f, 0.f, 0.f, 0.f};
    #pragma unroll
    for (int ks = 0; ks < 10; ++ks) {
        s16x8 af[4], bf[4];
        #pragma unroll
        for (int rt = 0; rt < 4; ++rt)
            af[rt] = *reinterpret_cast<const s16x8*>(&Mb[(size_t)arow[rt] * 320 + ks * 32 + g * 8]);
        #pragma unroll
        for (int ct = 0; ct < 4; ++ct) {
            int col = w * 64 + ct * 16 + c16;
            bf[ct] = *reinterpret_cast<const s16x8*>(&WtD[(size_t)col * 320 + ks * 32 + g * 8]);
        }
        #pragma unroll
        for (int rt = 0; rt < 4; ++rt)
            #pragma unroll
            for (int ct = 0; ct < 4; ++ct)
                acc[rt][ct] = __builtin_amdgcn_mfma_f32_16x16x32_bf16(af[rt], bf[ct], acc[rt][ct], 0, 0, 0);
    }
    // epilogue: sigmoid + bf16 store. C layout: col=c16, row=(g)*4+j within 16x16 tile.
    #pragma unroll
    for (int rt = 0; rt < 4; ++rt) {
        #pragma unroll
        for (int j = 0; j < 4; ++j) {
            int r = rows[rt * 16 + g * 4 + j];
            if (r >= 0) {
                #pragma unroll
                for (int ct = 0; ct < 4; ++ct) {
                    float v = sig1(acc[rt][ct][j]);
                    houtb[(size_t)r * 256 + w * 64 + ct * 16 + c16] = f2bf(v);
                }
            }
        }
    }
}

// -------- K3: readout via MFMA, LDS-free operands. Block = (batch, layer). --------
// 4 waves; wave w -> cols w*128..+127 (8 col-tiles), all 64 rows (4 row-tiles).
// exp without max-sub (|z| small), mask from degidx, cross-wave row-sums in LDS.
__global__ __launch_bounds__(256) void k_readout_mfma(
        const unsigned short* __restrict__ hb0,
        const unsigned short* __restrict__ hb1,
        const unsigned short* __restrict__ hb2,
        const unsigned short* __restrict__ Rt,   // [3][512][256] bf16
        const int* __restrict__ degidx,
        float* __restrict__ acc3) {
    const int b = blockIdx.x, layer = blockIdx.y;
    const unsigned short* hb = (layer == 0) ? hb0 : ((layer == 1) ? hb1 : hb2);
    const unsigned short* RtL = Rt + (size_t)layer * 512 * 256;
    __shared__ float red2[4][64];
    __shared__ __align__(16) float red3[64];
    __shared__ float flags[64];
    const int tid = threadIdx.x;
    const int w = tid >> 6, lane = tid & 63, g = lane >> 4, c16 = lane & 15;
    if (tid < 64)
        flags[tid] = (layer == 0) ? 1.f : ((degidx[b * 64 + tid] >= 0) ? 1.f : 0.f);
    f32x4 acc[4][8];
    #pragma unroll
    for (int rt = 0; rt < 4; ++rt)
        #pragma unroll
        for (int ct = 0; ct < 8; ++ct) acc[rt][ct] = (f32x4){0.f, 0.f, 0.f, 0.f};
    #pragma unroll
    for (int ks = 0; ks < 8; ++ks) {
        s16x8 af[4], bf[8];
        #pragma unroll
        for (int rt = 0; rt < 4; ++rt)
            af[rt] = *reinterpret_cast<const s16x8*>(
                &hb[((size_t)(b * 64 + rt * 16 + c16)) * 256 + ks * 32 + g * 8]);
        #pragma unroll
        for (int ct = 0; ct < 8; ++ct) {
            int col = w * 128 + ct * 16 + c16;
            bf[ct] = *reinterpret_cast<const s16x8*>(&RtL[(size_t)col * 256 + ks * 32 + g * 8]);
        }
        #pragma unroll
        for (int rt = 0; rt < 4; ++rt)
            #pragma unroll
            for (int ct = 0; ct < 8; ++ct)
                acc[rt][ct] = __builtin_amdgcn_mfma_f32_16x16x32_bf16(af[rt], bf[ct], acc[rt][ct], 0, 0, 0);
    }
    // exp in place; per-row partial sums over this wave's 128 cols
    float rs[4][4];
    #pragma unroll
    for (int rt = 0; rt < 4; ++rt) {
        #pragma unroll
        for (int j = 0; j < 4; ++j) rs[rt][j] = 0.f;
        #pragma unroll
        for (int ct = 0; ct < 8; ++ct) {
            #pragma unroll
            for (int j = 0; j < 4; ++j) {
                float p = __expf(acc[rt][ct][j]);
                acc[rt][ct][j] = p;
                rs[rt][j] += p;
            }
        }
    }
    #pragma unroll
    for (int rt = 0; rt < 4; ++rt)
        #pragma unroll
        for (int j = 0; j < 4; ++j) {
            float s = rs[rt][j];
            #pragma unroll
            for (int m = 1; m <= 8; m <<= 1) s += __shfl_xor(s, m);
            rs[rt][j] = s;
        }
    if (c16 == 0) {
        #pragma unroll
        for (int rt = 0; rt < 4; ++rt)
            #pragma unroll
            for (int j = 0; j < 4; ++j)
                red2[w][rt * 16 + g * 4 + j] = rs[rt][j];
    }
    __syncthreads();
    if (tid < 64) {
        float s = red2[0][tid] + red2[1][tid] + red2[2][tid] + red2[3][tid];
        red3[tid] = flags[tid] / s;   // s > 0 always (sum of exps)
    }
    __syncthreads();
    // scale + column sums
    f32x4 iv[4];
    #pragma unroll
    for (int rt = 0; rt < 4; ++rt)
        iv[rt] = *reinterpret_cast<const f32x4*>(&red3[rt * 16 + g * 4]);
    float cs[8];
    #pragma unroll
    for (int ct = 0; ct < 8; ++ct) {
        f32x4 t = (f32x4){0.f, 0.f, 0.f, 0.f};
        #pragma unroll
        for (int rt = 0; rt < 4; ++rt) t += acc[rt][ct] * iv[rt];
        float v = t[0] + t[1] + t[2] + t[3];
        v += __shfl_xor(v, 16);
        v += __shfl_xor(v, 32);
        cs[ct] = v;
    }
    if (lane < 16) {
        float* o = acc3 + ((size_t)layer * BB + b) * 512 + w * 128;
        #pragma unroll
        for (int ct = 0; ct < 8; ++ct) o[ct * 16 + lane] = cs[ct];
    }
}

// -------- K4: per-graph MLP head --------
__global__ __launch_bounds__(128) void k_mlp(const float* __restrict__ acc3,
                                             const float* __restrict__ fc0w, const float* __restrict__ fc0b,
                                             const float* __restrict__ fc1w, const float* __restrict__ fc1b,
                                             const float* __restrict__ fc2w, const float* __restrict__ fc2b,
                                             const float* __restrict__ fc3w, const float* __restrict__ fc3b,
                                             float* __restrict__ out) {
    const int b = blockIdx.x;
    const int tid = threadIdx.x;
    __shared__ float x0[512], x1[128], x2[256], x3[128];
    #pragma unroll
    for (int j = 0; j < 4; ++j) {
        int i = j * 128 + tid;
        x0[i] = acc3[(size_t)b * 512 + i]
              + acc3[((size_t)BB + b) * 512 + i]
              + acc3[((size_t)2 * BB + b) * 512 + i];
    }
    __syncthreads();
    {
        float a = fc0b[tid];
        for (int i = 0; i < 512; ++i) a = fmaf(x0[i], fc0w[i * 128 + tid], a);
        x1[tid] = fmaxf(a, 0.f);
    }
    __syncthreads();
    #pragma unroll
    for (int oo = 0; oo < 2; ++oo) {
        int o = oo * 128 + tid;
        float a = fc1b[o];
        for (int i = 0; i < 128; ++i) a = fmaf(x1[i], fc1w[i * 256 + o], a);
        x2[o] = fmaxf(a, 0.f);
    }
    __syncthreads();
    {
        float a = fc2b[tid];
        for (int i = 0; i < 256; ++i) a = fmaf(x2[i], fc2w[i * 128 + tid], a);
        x3[tid] = fmaxf(a, 0.f);
    }
    __syncthreads();
    if (tid < TGT) {
        float a = fc3b[tid];
        for (int i = 0; i < 128; ++i) a = fmaf(x3[i], fc3w[i * TGT + tid], a);
        out[(size_t)b * TGT + tid] = a;
    }
}

extern "C" void kernel_launch(void* const* d_in, const int* in_sizes, int n_in,
                              void* d_out, int out_size, void* d_ws, size_t ws_size,
                              hipStream_t stream) {
    (void)in_sizes; (void)n_in; (void)out_size; (void)ws_size;
    const float* g    = (const float*)d_in[0];
    const float* h_in = (const float*)d_in[1];
    const float* e    = (const float*)d_in[2];
    const float* Wu0  = (const float*)d_in[3];
    const float* Wu1  = (const float*)d_in[4];
    const float* R    = (const float*)d_in[5];
    const float* fc0w = (const float*)d_in[6];
    const float* fc0b = (const float*)d_in[7];
    const float* fc1w = (const float*)d_in[8];
    const float* fc1b = (const float*)d_in[9];
    const float* fc2w = (const float*)d_in[10];
    const float* fc2b = (const float*)d_in[11];
    const float* fc3w = (const float*)d_in[12];
    const float* fc3b = (const float*)d_in[13];
    float* out = (float*)d_out;

    char* p = (char*)d_ws;
    unsigned short* Mb  = (unsigned short*)p; p += (size_t)NNODES * 320 * 2;     // 10 MB
    unsigned short* hb0 = (unsigned short*)p; p += (size_t)NNODES * 256 * 2;     // 8 MB
    unsigned short* hb1 = (unsigned short*)p; p += (size_t)NNODES * 256 * 2;     // 8 MB
    unsigned short* hb2 = (unsigned short*)p; p += (size_t)NNODES * 256 * 2;     // 8 MB
    unsigned short* Rt  = (unsigned short*)p; p += (size_t)3 * 512 * 256 * 2;    // 0.75 MB
    unsigned short* Wt0 = (unsigned short*)p; p += (size_t)ND * 256 * 320 * 2;   // 1.8 MB
    unsigned short* Wt1 = (unsigned short*)p; p += (size_t)ND * 256 * 320 * 2;   // 1.8 MB
    float* acc3 = (float*)p;                  p += (size_t)3 * BB * 512 * 4;     // 1.5 MB
    int* degidx = (int*)p;                    p += (size_t)NNODES * 4;
    int* counts = (int*)p;                    p += 256;
    int* lists  = (int*)p;                    p += (size_t)ND * NNODES * 4;

    k_me_deg<<<NNODES / 4, 256, 0, stream>>>(g, e, Mb, degidx, counts);
    k_build_lists<<<NNODES / 256, 256, 0, stream>>>(degidx, counts, lists, hb1, hb2);
    k_cvt_h<<<NNODES * 256 / 4 / 256, 256, 0, stream>>>(h_in, hb0);
    k_cvt_R<<<dim3(32, 3), 256, 0, stream>>>(R, Rt);
    k_cvt_W<<<dim3(20, ND), 256, 0, stream>>>(Wu0, Wt0);
    k_cvt_W<<<dim3(20, ND), 256, 0, stream>>>(Wu1, Wt1);

    k_mh<false><<<BB, 256, 0, stream>>>(g, h_in, Mb);
    k_update_mfma<<<dim3(256, ND), 256, 0, stream>>>(Mb, Wt0, lists, counts, hb1);

    k_mh<true><<<BB, 256, 0, stream>>>(g, hb1, Mb);
    k_update_mfma<<<dim3(256, ND), 256, 0, stream>>>(Mb, Wt1, lists, counts, hb2);

    k_readout_mfma<<<dim3(BB, 3), 256, 0, stream>>>(hb0, hb1, hb2, Rt, degidx, acc3);

    k_mlp<<<BB, 128, 0, stream>>>(acc3, fc0w, fc0b, fc1w, fc1b, fc2w, fc2b, fc3w, fc3b, out);
}

// Round 4
// 282.044 us; speedup vs baseline: 1.7253x; 1.0676x over previous
//
#include <hip/hip_runtime.h>
#include <hip/hip_bf16.h>

#define BB 256
#define NN 64
#define NNODES 16384   // BB*NN
#define ND 11
#define TGT 12

// k_prep role bases
#define NB_MEDEG 4096
#define NB_CVTH  2048
#define NB_CVTR  96
#define NB_CVTW  220
#define NB_MH0   256
#define NB_TOTAL (NB_MEDEG + NB_CVTH + NB_CVTR + 2 * NB_CVTW + NB_MH0)

typedef __attribute__((ext_vector_type(8))) short s16x8;
typedef __attribute__((ext_vector_type(4))) float f32x4;

__device__ __forceinline__ void fma4(float4& a, float s, const float4 b) {
    a.x = fmaf(s, b.x, a.x); a.y = fmaf(s, b.y, a.y);
    a.z = fmaf(s, b.z, a.z); a.w = fmaf(s, b.w, a.w);
}
__device__ __forceinline__ float sig1(float v) { return 1.f / (1.f + __expf(-v)); }
__device__ __forceinline__ float bf2f(unsigned short u) {
    union { unsigned int i; float f; } v; v.i = ((unsigned int)u) << 16; return v.f;
}
__device__ __forceinline__ unsigned short f2bf(float f) {
    __hip_bfloat16 b = __float2bfloat16(f);   // RNE
    return *reinterpret_cast<unsigned short*>(&b);
}

// ================= D1: mega-prep =================
// roles: [me_deg | cvt_h | cvt_R | cvt_W0 | cvt_W1 | mh0]
__global__ __launch_bounds__(256) void k_prep(
        const float* __restrict__ g, const float* __restrict__ e,
        const float* __restrict__ h_in, const float* __restrict__ R,
        const float* __restrict__ Wu0, const float* __restrict__ Wu1,
        unsigned short* __restrict__ Mb, unsigned short* __restrict__ hb0,
        unsigned short* __restrict__ Rt, unsigned short* __restrict__ Wt0,
        unsigned short* __restrict__ Wt1,
        int* __restrict__ degidx, int* __restrict__ counts) {
    __shared__ __align__(16) unsigned char smem[33024];
    int bid = blockIdx.x;
    const int tid = threadIdx.x;

    if (bid < NB_MEDEG) {
        // ---- me_deg: deg + m_e -> Mb cols 256..319 (bf16); zero counts ----
        if (bid == 0 && tid < 16) counts[tid] = 0;
        const int lane = tid & 63;
        const int node = bid * 4 + (tid >> 6);
        const float gv = g[(size_t)node * 64 + lane];
        float deg = gv;
        #pragma unroll
        for (int m = 32; m >= 1; m >>= 1) deg += __shfl_xor(deg, m);
        if (lane == 0) {
            int di = (int)(deg + 0.5f);
            degidx[node] = (di < ND) ? di : -1;
        }
        const int wsub = lane >> 4;
        const int cg = lane & 15;
        const float4* e4 = reinterpret_cast<const float4*>(e) + (size_t)node * 1024;
        float4 acc = make_float4(0.f, 0.f, 0.f, 0.f);
        #pragma unroll 4
        for (int w0 = 0; w0 < 64; w0 += 4) {
            int w = w0 + wsub;
            float gw = __shfl(gv, w);
            float4 ev = e4[w * 16 + cg];
            fma4(acc, gw, ev);
        }
        acc.x += __shfl_xor(acc.x, 16); acc.y += __shfl_xor(acc.y, 16);
        acc.z += __shfl_xor(acc.z, 16); acc.w += __shfl_xor(acc.w, 16);
        acc.x += __shfl_xor(acc.x, 32); acc.y += __shfl_xor(acc.y, 32);
        acc.z += __shfl_xor(acc.z, 32); acc.w += __shfl_xor(acc.w, 32);
        if (lane < 16) {
            ushort4 u = make_ushort4(f2bf(acc.x), f2bf(acc.y), f2bf(acc.z), f2bf(acc.w));
            *reinterpret_cast<ushort4*>(&Mb[(size_t)node * 320 + 256 + cg * 4]) = u;
        }
        return;
    }
    bid -= NB_MEDEG;

    if (bid < NB_CVTH) {
        // ---- cvt_h: h_in f32 -> hb0 bf16, 8 elems/thread ----
        size_t idx = (size_t)bid * 256 + tid;
        const float4* src = reinterpret_cast<const float4*>(h_in);
        float4 v0 = src[idx * 2], v1 = src[idx * 2 + 1];
        ushort4 a = make_ushort4(f2bf(v0.x), f2bf(v0.y), f2bf(v0.z), f2bf(v0.w));
        ushort4 b = make_ushort4(f2bf(v1.x), f2bf(v1.y), f2bf(v1.z), f2bf(v1.w));
        ushort4* dst = reinterpret_cast<ushort4*>(hb0);
        dst[idx * 2] = a; dst[idx * 2 + 1] = b;
        return;
    }
    bid -= NB_CVTH;

    if (bid < NB_CVTR) {
        // ---- cvt_R: R [3][256][512] f32 -> Rt [3][512][256] bf16 ----
        float (*st)[65] = reinterpret_cast<float (*)[65]>(smem);
        const int l = bid >> 5, xx = bid & 31;
        const int kt = (xx & 3) * 64, nt = (xx >> 2) * 64;
        const int tx = tid & 63, ty = tid >> 6;
        const float* Rl = R + (size_t)l * 256 * 512;
        #pragma unroll
        for (int j = 0; j < 16; ++j) {
            int kl = ty + j * 4;
            st[kl][tx] = Rl[(size_t)(kt + kl) * 512 + nt + tx];
        }
        __syncthreads();
        unsigned short* RtL = Rt + (size_t)l * 512 * 256;
        #pragma unroll
        for (int j = 0; j < 16; ++j) {
            int nl = ty + j * 4;
            RtL[(size_t)(nt + nl) * 256 + kt + tx] = f2bf(st[tx][nl]);
        }
        return;
    }
    bid -= NB_CVTR;

    if (bid < 2 * NB_CVTW) {
        // ---- cvt_W: W [ND][320][256] f32 -> Wt [ND][256][320] bf16 ----
        float (*st)[65] = reinterpret_cast<float (*)[65]>(smem);
        const float* W = (bid < NB_CVTW) ? Wu0 : Wu1;
        unsigned short* Wt = (bid < NB_CVTW) ? Wt0 : Wt1;
        int wb = (bid < NB_CVTW) ? bid : (bid - NB_CVTW);
        const int d = wb / 20, t = wb % 20;
        const int kt = (t % 5) * 64, ct = (t / 5) * 64;
        const int tx = tid & 63, ty = tid >> 6;
        const float* Wd = W + (size_t)d * 320 * 256;
        #pragma unroll
        for (int j = 0; j < 16; ++j) {
            int kl = ty + j * 4;
            st[kl][tx] = Wd[(size_t)(kt + kl) * 256 + ct + tx];
        }
        __syncthreads();
        unsigned short* Wo = Wt + (size_t)d * 256 * 320;
        #pragma unroll
        for (int j = 0; j < 16; ++j) {
            int cl = ty + j * 4;
            Wo[(size_t)(ct + cl) * 320 + kt + tx] = f2bf(st[tx][cl]);
        }
        return;
    }
    bid -= 2 * NB_CVTW;

    // ---- mh0: sparse m_h = sum of neighbor h_in rows -> Mb cols 0..255 ----
    {
        unsigned short* hs = reinterpret_cast<unsigned short*>(smem);  // [64][256] bf16
        const int b = bid;
        const float4* hin4 = reinterpret_cast<const float4*>(h_in) + (size_t)b * 4096;
        #pragma unroll
        for (int j = 0; j < 16; ++j) {
            int i = j * 256 + tid;
            float4 v = hin4[i];
            ushort4 u = make_ushort4(f2bf(v.x), f2bf(v.y), f2bf(v.z), f2bf(v.w));
            *reinterpret_cast<ushort4*>(&hs[i * 4]) = u;
        }
        __syncthreads();
        const int wv = tid >> 6, lane = tid & 63;
        for (int s = 0; s < 16; ++s) {
            const int v = wv * 16 + s;
            float gval = g[((size_t)b * 64 + v) * 64 + lane];
            unsigned long long mask = __ballot(gval != 0.f);
            if (__popcll(mask) > 10) continue;   // invalid degree: Mb row unused
            float4 acc = make_float4(0.f, 0.f, 0.f, 0.f);
            while (mask) {
                int w = __builtin_ctzll(mask); mask &= mask - 1;
                ushort4 hv = *reinterpret_cast<const ushort4*>(&hs[w * 256 + lane * 4]);
                acc.x += bf2f(hv.x); acc.y += bf2f(hv.y);
                acc.z += bf2f(hv.z); acc.w += bf2f(hv.w);
            }
            ushort4 u = make_ushort4(f2bf(acc.x), f2bf(acc.y), f2bf(acc.z), f2bf(acc.w));
            *reinterpret_cast<ushort4*>(&Mb[((size_t)b * 64 + v) * 320 + lane * 4]) = u;
        }
    }
}

// ================= D2: buckets + zero invalid hb rows =================
__global__ __launch_bounds__(256) void k_build_lists(const int* __restrict__ degidx,
                                                     int* __restrict__ counts,
                                                     int* __restrict__ lists,
                                                     unsigned short* __restrict__ hb1,
                                                     unsigned short* __restrict__ hb2) {
    int node = blockIdx.x * 256 + threadIdx.x;
    int d = degidx[node];
    if (d >= 0) {
        int pos = atomicAdd(&counts[d], 1);
        lists[d * NNODES + pos] = node;
    } else {
        uint4 z = make_uint4(0, 0, 0, 0);
        uint4* p1 = reinterpret_cast<uint4*>(&hb1[(size_t)node * 256]);
        uint4* p2 = reinterpret_cast<uint4*>(&hb2[(size_t)node * 256]);
        #pragma unroll
        for (int j = 0; j < 32; ++j) { p1[j] = z; p2[j] = z; }
    }
}

// ================= D4: sparse m_h from bf16 h =================
__global__ __launch_bounds__(256) void k_mh_sparse(const float* __restrict__ g,
                                                   const unsigned short* __restrict__ hb,
                                                   unsigned short* __restrict__ Mb) {
    __shared__ __align__(16) unsigned short hs[NN * 256];   // 32 KB
    const int b = blockIdx.x;
    const int tid = threadIdx.x;
    {
        const uint4* src = reinterpret_cast<const uint4*>(hb) + (size_t)b * 2048;
        uint4* dst = reinterpret_cast<uint4*>(hs);
        #pragma unroll
        for (int j = 0; j < 8; ++j) dst[j * 256 + tid] = src[j * 256 + tid];
    }
    __syncthreads();
    const int wv = tid >> 6, lane = tid & 63;
    for (int s = 0; s < 16; ++s) {
        const int v = wv * 16 + s;
        float gval = g[((size_t)b * 64 + v) * 64 + lane];
        unsigned long long mask = __ballot(gval != 0.f);
        if (__popcll(mask) > 10) continue;
        float4 acc = make_float4(0.f, 0.f, 0.f, 0.f);
        while (mask) {
            int w = __builtin_ctzll(mask); mask &= mask - 1;
            ushort4 hv = *reinterpret_cast<const ushort4*>(&hs[w * 256 + lane * 4]);
            acc.x += bf2f(hv.x); acc.y += bf2f(hv.y);
            acc.z += bf2f(hv.z); acc.w += bf2f(hv.w);
        }
        ushort4 u = make_ushort4(f2bf(acc.x), f2bf(acc.y), f2bf(acc.z), f2bf(acc.w));
        *reinterpret_cast<ushort4*>(&Mb[((size_t)b * 64 + v) * 320 + lane * 4]) = u;
    }
}

// ================= D3/D5: grouped update via MFMA =================
__global__ __launch_bounds__(256) void k_update_mfma(
        const unsigned short* __restrict__ Mb,
        const unsigned short* __restrict__ Wt,
        const int* __restrict__ lists,
        const int* __restrict__ counts,
        unsigned short* __restrict__ houtb) {
    const int d = blockIdx.y;
    const int cnt = counts[d];
    const int base = blockIdx.x * 64;
    if (base >= cnt) return;
    __shared__ int rows[64];
    const int tid = threadIdx.x;
    if (tid < 64) {
        int i = base + tid;
        rows[tid] = (i < cnt) ? lists[d * NNODES + i] : -1;
    }
    __syncthreads();
    const int w = tid >> 6, lane = tid & 63;
    const int gq = lane >> 4, c16 = lane & 15;
    const unsigned short* WtD = Wt + (size_t)d * 256 * 320;
    int arow[4];
    #pragma unroll
    for (int rt = 0; rt < 4; ++rt) {
        int r = rows[rt * 16 + c16];
        arow[rt] = (r < 0) ? 0 : r;
    }
    f32x4 acc[4][4];
    #pragma unroll
    for (int rt = 0; rt < 4; ++rt)
        #pragma unroll
        for (int ct = 0; ct < 4; ++ct) acc[rt][ct] = (f32x4){0.f, 0.f, 0.f, 0.f};
    #pragma unroll
    for (int ks = 0; ks < 10; ++ks) {
        s16x8 af[4], bf[4];
        #pragma unroll
        for (int rt = 0; rt < 4; ++rt)
            af[rt] = *reinterpret_cast<const s16x8*>(&Mb[(size_t)arow[rt] * 320 + ks * 32 + gq * 8]);
        #pragma unroll
        for (int ct = 0; ct < 4; ++ct) {
            int col = w * 64 + ct * 16 + c16;
            bf[ct] = *reinterpret_cast<const s16x8*>(&WtD[(size_t)col * 320 + ks * 32 + gq * 8]);
        }
        #pragma unroll
        for (int rt = 0; rt < 4; ++rt)
            #pragma unroll
            for (int ct = 0; ct < 4; ++ct)
                acc[rt][ct] = __builtin_amdgcn_mfma_f32_16x16x32_bf16(af[rt], bf[ct], acc[rt][ct], 0, 0, 0);
    }
    #pragma unroll
    for (int rt = 0; rt < 4; ++rt) {
        #pragma unroll
        for (int j = 0; j < 4; ++j) {
            int r = rows[rt * 16 + gq * 4 + j];
            if (r >= 0) {
                #pragma unroll
                for (int ct = 0; ct < 4; ++ct) {
                    float v = sig1(acc[rt][ct][j]);
                    houtb[(size_t)r * 256 + w * 64 + ct * 16 + c16] = f2bf(v);
                }
            }
        }
    }
}

// ================= D6: readout (3 layers) + MLP, block = batch =================
__global__ __launch_bounds__(256) void k_readout_mlp(
        const unsigned short* __restrict__ hb0,
        const unsigned short* __restrict__ hb1,
        const unsigned short* __restrict__ hb2,
        const unsigned short* __restrict__ Rt,   // [3][512][256] bf16
        const int* __restrict__ degidx,
        const float* __restrict__ fc0w, const float* __restrict__ fc0b,
        const float* __restrict__ fc1w, const float* __restrict__ fc1b,
        const float* __restrict__ fc2w, const float* __restrict__ fc2b,
        const float* __restrict__ fc3w, const float* __restrict__ fc3b,
        float* __restrict__ out) {
    const int b = blockIdx.x;
    const int tid = threadIdx.x;
    const int w = tid >> 6, lane = tid & 63, gq = lane >> 4, c16 = lane & 15;
    __shared__ float x0[512];
    __shared__ float red2[4][64];
    __shared__ __align__(16) float red3[64];
    __shared__ float flags[64];
    __shared__ float part[256];
    __shared__ float x1[128], x2[256], x3[128];
    if (tid < 64) flags[tid] = (degidx[b * 64 + tid] >= 0) ? 1.f : 0.f;
    x0[tid] = 0.f; x0[tid + 256] = 0.f;

    for (int layer = 0; layer < 3; ++layer) {
        const unsigned short* hb = (layer == 0) ? hb0 : ((layer == 1) ? hb1 : hb2);
        const unsigned short* RtL = Rt + (size_t)layer * 512 * 256;
        f32x4 acc[4][8];
        #pragma unroll
        for (int rt = 0; rt < 4; ++rt)
            #pragma unroll
            for (int ct = 0; ct < 8; ++ct) acc[rt][ct] = (f32x4){0.f, 0.f, 0.f, 0.f};
        #pragma unroll
        for (int ks = 0; ks < 8; ++ks) {
            s16x8 af[4], bf[8];
            #pragma unroll
            for (int rt = 0; rt < 4; ++rt)
                af[rt] = *reinterpret_cast<const s16x8*>(
                    &hb[((size_t)(b * 64 + rt * 16 + c16)) * 256 + ks * 32 + gq * 8]);
            #pragma unroll
            for (int ct = 0; ct < 8; ++ct) {
                int col = w * 128 + ct * 16 + c16;
                bf[ct] = *reinterpret_cast<const s16x8*>(&RtL[(size_t)col * 256 + ks * 32 + gq * 8]);
            }
            #pragma unroll
            for (int rt = 0; rt < 4; ++rt)
                #pragma unroll
                for (int ct = 0; ct < 8; ++ct)
                    acc[rt][ct] = __builtin_amdgcn_mfma_f32_16x16x32_bf16(af[rt], bf[ct], acc[rt][ct], 0, 0, 0);
        }
        // exp in place; per-row partial sums over this wave's 128 cols
        float rs[4][4];
        #pragma unroll
        for (int rt = 0; rt < 4; ++rt) {
            #pragma unroll
            for (int j = 0; j < 4; ++j) rs[rt][j] = 0.f;
            #pragma unroll
            for (int ct = 0; ct < 8; ++ct) {
                #pragma unroll
                for (int j = 0; j < 4; ++j) {
                    float p = __expf(acc[rt][ct][j]);
                    acc[rt][ct][j] = p;
                    rs[rt][j] += p;
                }
            }
        }
        #pragma unroll
        for (int rt = 0; rt < 4; ++rt)
            #pragma unroll
            for (int j = 0; j < 4; ++j) {
                float s = rs[rt][j];
                #pragma unroll
                for (int m = 1; m <= 8; m <<= 1) s += __shfl_xor(s, m);
                rs[rt][j] = s;
            }
        if (c16 == 0) {
            #pragma unroll
            for (int rt = 0; rt < 4; ++rt)
                #pragma unroll
                for (int j = 0; j < 4; ++j)
                    red2[w][rt * 16 + gq * 4 + j] = rs[rt][j];
        }
        __syncthreads();
        if (tid < 64) {
            float s = red2[0][tid] + red2[1][tid] + red2[2][tid] + red2[3][tid];
            red3[tid] = ((layer == 0) ? 1.f : flags[tid]) / s;
        }
        __syncthreads();
        f32x4 iv[4];
        #pragma unroll
        for (int rt = 0; rt < 4; ++rt)
            iv[rt] = *reinterpret_cast<const f32x4*>(&red3[rt * 16 + gq * 4]);
        #pragma unroll
        for (int ct = 0; ct < 8; ++ct) {
            f32x4 t = (f32x4){0.f, 0.f, 0.f, 0.f};
            #pragma unroll
            for (int rt = 0; rt < 4; ++rt) t += acc[rt][ct] * iv[rt];
            float v = t[0] + t[1] + t[2] + t[3];
            v += __shfl_xor(v, 16);
            v += __shfl_xor(v, 32);
            if (lane < 16) x0[w * 128 + ct * 16 + lane] += v;
        }
        __syncthreads();
    }
    // ---- MLP on x0[512] ----
    {
        const int o = tid & 127, half = tid >> 7;
        float a = 0.f;
        const int i0 = half * 256;
        for (int i = 0; i < 256; ++i) a = fmaf(x0[i0 + i], fc0w[(size_t)(i0 + i) * 128 + o], a);
        part[tid] = a;
    }
    __syncthreads();
    if (tid < 128) x1[tid] = fmaxf(fc0b[tid] + part[tid] + part[tid + 128], 0.f);
    __syncthreads();
    {
        float a = fc1b[tid];
        for (int i = 0; i < 128; ++i) a = fmaf(x1[i], fc1w[(size_t)i * 256 + tid], a);
        x2[tid] = fmaxf(a, 0.f);
    }
    __syncthreads();
    {
        const int o = tid & 127, half = tid >> 7;
        float a = 0.f;
        const int i0 = half * 128;
        for (int i = 0; i < 128; ++i) a = fmaf(x2[i0 + i], fc2w[(size_t)(i0 + i) * 128 + o], a);
        part[tid] = a;
    }
    __syncthreads();
    if (tid < 128) x3[tid] = fmaxf(fc2b[tid] + part[tid] + part[tid + 128], 0.f);
    __syncthreads();
    if (tid < TGT) {
        float a = fc3b[tid];
        for (int i = 0; i < 128; ++i) a = fmaf(x3[i], fc3w[(size_t)i * TGT + tid], a);
        out[(size_t)b * TGT + tid] = a;
    }
}

extern "C" void kernel_launch(void* const* d_in, const int* in_sizes, int n_in,
                              void* d_out, int out_size, void* d_ws, size_t ws_size,
                              hipStream_t stream) {
    (void)in_sizes; (void)n_in; (void)out_size; (void)ws_size;
    const float* g    = (const float*)d_in[0];
    const float* h_in = (const float*)d_in[1];
    const float* e    = (const float*)d_in[2];
    const float* Wu0  = (const float*)d_in[3];
    const float* Wu1  = (const float*)d_in[4];
    const float* R    = (const float*)d_in[5];
    const float* fc0w = (const float*)d_in[6];
    const float* fc0b = (const float*)d_in[7];
    const float* fc1w = (const float*)d_in[8];
    const float* fc1b = (const float*)d_in[9];
    const float* fc2w = (const float*)d_in[10];
    const float* fc2b = (const float*)d_in[11];
    const float* fc3w = (const float*)d_in[12];
    const float* fc3b = (const float*)d_in[13];
    float* out = (float*)d_out;

    char* p = (char*)d_ws;
    unsigned short* Mb  = (unsigned short*)p; p += (size_t)NNODES * 320 * 2;     // 10 MB
    unsigned short* hb0 = (unsigned short*)p; p += (size_t)NNODES * 256 * 2;     // 8 MB
    unsigned short* hb1 = (unsigned short*)p; p += (size_t)NNODES * 256 * 2;     // 8 MB
    unsigned short* hb2 = (unsigned short*)p; p += (size_t)NNODES * 256 * 2;     // 8 MB
    unsigned short* Rt  = (unsigned short*)p; p += (size_t)3 * 512 * 256 * 2;    // 0.75 MB
    unsigned short* Wt0 = (unsigned short*)p; p += (size_t)ND * 256 * 320 * 2;   // 1.76 MB
    unsigned short* Wt1 = (unsigned short*)p; p += (size_t)ND * 256 * 320 * 2;   // 1.76 MB
    int* degidx = (int*)p;                    p += (size_t)NNODES * 4;           // 64 KB
    int* counts = (int*)p;                    p += 1024;
    int* lists  = (int*)p;                    p += (size_t)ND * NNODES * 4;      // 720 KB

    k_prep<<<NB_TOTAL, 256, 0, stream>>>(g, e, h_in, R, Wu0, Wu1,
                                         Mb, hb0, Rt, Wt0, Wt1, degidx, counts);
    k_build_lists<<<NNODES / 256, 256, 0, stream>>>(degidx, counts, lists, hb1, hb2);
    k_update_mfma<<<dim3(256, ND), 256, 0, stream>>>(Mb, Wt0, lists, counts, hb1);
    k_mh_sparse<<<BB, 256, 0, stream>>>(g, hb1, Mb);
    k_update_mfma<<<dim3(256, ND), 256, 0, stream>>>(Mb, Wt1, lists, counts, hb2);
    k_readout_mlp<<<BB, 256, 0, stream>>>(hb0, hb1, hb2, Rt, degidx,
                                          fc0w, fc0b, fc1w, fc1b, fc2w, fc2b, fc3w, fc3b, out);
}

// Round 6
// 229.790 us; speedup vs baseline: 2.1176x; 1.2274x over previous
//
#include <hip/hip_runtime.h>
#include <hip/hip_bf16.h>

#define BB 256
#define NN 64
#define NNODES 16384   // BB*NN
#define ND 11
#define TGT 12

// k_prep role bases
#define NB_MEDEG 4096
#define NB_CVTH  2048
#define NB_CVTR  96
#define NB_CVTW  352
#define NB_MH0   256
#define NB_TOTAL (NB_MEDEG + NB_CVTH + NB_CVTR + NB_CVTW + NB_MH0)

typedef __attribute__((ext_vector_type(8))) short s16x8;
typedef __attribute__((ext_vector_type(4))) float f32x4;

__device__ __forceinline__ void fma4(float4& a, float s, const float4 b) {
    a.x = fmaf(s, b.x, a.x); a.y = fmaf(s, b.y, a.y);
    a.z = fmaf(s, b.z, a.z); a.w = fmaf(s, b.w, a.w);
}
__device__ __forceinline__ float sig1(float v) { return 1.f / (1.f + __expf(-v)); }
__device__ __forceinline__ float bf2f(unsigned short u) {
    union { unsigned int i; float f; } v; v.i = ((unsigned int)u) << 16; return v.f;
}
__device__ __forceinline__ unsigned short f2bf(float f) {
    __hip_bfloat16 b = __float2bfloat16(f);   // RNE
    return *reinterpret_cast<unsigned short*>(&b);
}

// ================= D1: mega-prep =================
// roles: [me_deg | cvt_h | cvt_R | cvt_W(0+1) | mh0]
// Wtf layout: [d][cb=16][ks=10][lane=64][8]  (B-fragment order, coalesced)
// Rtf layout: [l][cb=32][ks=8 ][lane=64][8]
__global__ __launch_bounds__(256) void k_prep(
        const float* __restrict__ g, const float* __restrict__ e,
        const float* __restrict__ h_in, const float* __restrict__ R,
        const float* __restrict__ Wu0, const float* __restrict__ Wu1,
        unsigned short* __restrict__ Mb, unsigned short* __restrict__ hb0,
        unsigned short* __restrict__ Rtf, unsigned short* __restrict__ Wtf0,
        unsigned short* __restrict__ Wtf1, int* __restrict__ degidx) {
    __shared__ __align__(16) unsigned char smem[32768];
    int bid = blockIdx.x;
    const int tid = threadIdx.x;
    const int lane = tid & 63, wv = tid >> 6;
    const int gq = lane >> 4, c16 = lane & 15;

    if (bid < NB_MEDEG) {
        // ---- me_deg: deg + m_e -> Mb cols 256..319 (bf16, row-major) ----
        const int node = bid * 4 + wv;
        const float gv = g[(size_t)node * 64 + lane];
        float deg = gv;
        #pragma unroll
        for (int m = 32; m >= 1; m >>= 1) deg += __shfl_xor(deg, m);
        const int di = (int)(deg + 0.5f);
        if (lane == 0) degidx[node] = (di < ND) ? di : -1;
        if (di >= ND) return;   // invalid: m_e never consumed
        const int wsub = lane >> 4;
        const int cg = lane & 15;
        const float4* e4 = reinterpret_cast<const float4*>(e) + (size_t)node * 1024;
        float4 acc = make_float4(0.f, 0.f, 0.f, 0.f);
        #pragma unroll 4
        for (int w0 = 0; w0 < 64; w0 += 4) {
            int w = w0 + wsub;
            float gw = __shfl(gv, w);
            float4 ev = e4[w * 16 + cg];
            fma4(acc, gw, ev);
        }
        acc.x += __shfl_xor(acc.x, 16); acc.y += __shfl_xor(acc.y, 16);
        acc.z += __shfl_xor(acc.z, 16); acc.w += __shfl_xor(acc.w, 16);
        acc.x += __shfl_xor(acc.x, 32); acc.y += __shfl_xor(acc.y, 32);
        acc.z += __shfl_xor(acc.z, 32); acc.w += __shfl_xor(acc.w, 32);
        if (lane < 16) {
            ushort4 u = make_ushort4(f2bf(acc.x), f2bf(acc.y), f2bf(acc.z), f2bf(acc.w));
            *reinterpret_cast<ushort4*>(&Mb[(size_t)node * 320 + 256 + cg * 4]) = u;
        }
        return;
    }
    bid -= NB_MEDEG;

    if (bid < NB_CVTH) {
        // ---- cvt_h: h_in f32 -> hb0 bf16 (row-major) ----
        size_t idx = (size_t)bid * 256 + tid;
        const float4* src = reinterpret_cast<const float4*>(h_in);
        float4 v0 = src[idx * 2], v1 = src[idx * 2 + 1];
        ushort4 a = make_ushort4(f2bf(v0.x), f2bf(v0.y), f2bf(v0.z), f2bf(v0.w));
        ushort4 b = make_ushort4(f2bf(v1.x), f2bf(v1.y), f2bf(v1.z), f2bf(v1.w));
        ushort4* dst = reinterpret_cast<ushort4*>(hb0);
        dst[idx * 2] = a; dst[idx * 2 + 1] = b;
        return;
    }
    bid -= NB_CVTH;

    if (bid < NB_CVTR) {
        // ---- cvt_R -> fragment order ----
        const int l = bid >> 5, cb = bid & 31;
        const float* Rl = R + (size_t)l * 256 * 512;
        unsigned short* outB = Rtf + ((size_t)l * 32 + cb) * 8 * 512;
        const int col = cb * 16 + c16;
        #pragma unroll
        for (int it = 0; it < 2; ++it) {
            int ks = wv + it * 4;   // 0..7
            unsigned short tmp[8];
            #pragma unroll
            for (int j = 0; j < 8; ++j)
                tmp[j] = f2bf(Rl[(size_t)(ks * 32 + gq * 8 + j) * 512 + col]);
            *reinterpret_cast<uint4*>(&outB[(size_t)ks * 512 + lane * 8]) =
                *reinterpret_cast<const uint4*>(tmp);
        }
        return;
    }
    bid -= NB_CVTR;

    if (bid < NB_CVTW) {
        // ---- cvt_W -> fragment order ----
        const int wsel = bid / 176, rem = bid % 176;
        const int d = rem >> 4, cb = rem & 15;
        const float* Wd = (wsel ? Wu1 : Wu0) + (size_t)d * 320 * 256;
        unsigned short* outB = (wsel ? Wtf1 : Wtf0) + ((size_t)d * 16 + cb) * 10 * 512;
        const int col = cb * 16 + c16;
        #pragma unroll
        for (int it = 0; it < 3; ++it) {
            int ks = wv + it * 4;   // 0..11 -> keep <10
            if (ks < 10) {
                unsigned short tmp[8];
                #pragma unroll
                for (int j = 0; j < 8; ++j)
                    tmp[j] = f2bf(Wd[(size_t)(ks * 32 + gq * 8 + j) * 256 + col]);
                *reinterpret_cast<uint4*>(&outB[(size_t)ks * 512 + lane * 8]) =
                    *reinterpret_cast<const uint4*>(tmp);
            }
        }
        return;
    }
    bid -= NB_CVTW;

    // ---- mh0: sparse m_h from h_in -> Mb cols 0..255 ----
    {
        unsigned short* hs = reinterpret_cast<unsigned short*>(smem);  // [64][256] bf16
        const int b = bid;
        const float4* hin4 = reinterpret_cast<const float4*>(h_in) + (size_t)b * 4096;
        #pragma unroll
        for (int j = 0; j < 16; ++j) {
            int i = j * 256 + tid;
            float4 v = hin4[i];
            ushort4 u = make_ushort4(f2bf(v.x), f2bf(v.y), f2bf(v.z), f2bf(v.w));
            *reinterpret_cast<ushort4*>(&hs[i * 4]) = u;
        }
        __syncthreads();
        for (int s = 0; s < 16; ++s) {
            const int v = wv * 16 + s;
            float gval = g[((size_t)b * 64 + v) * 64 + lane];
            unsigned long long mask = __ballot(gval != 0.f);
            if (__popcll(mask) > 10) continue;   // invalid: row never consumed
            float4 acc = make_float4(0.f, 0.f, 0.f, 0.f);
            while (mask) {
                int w = __builtin_ctzll(mask); mask &= mask - 1;
                ushort4 hv = *reinterpret_cast<const ushort4*>(&hs[w * 256 + lane * 4]);
                acc.x += bf2f(hv.x); acc.y += bf2f(hv.y);
                acc.z += bf2f(hv.z); acc.w += bf2f(hv.w);
            }
            ushort4 u = make_ushort4(f2bf(acc.x), f2bf(acc.y), f2bf(acc.z), f2bf(acc.w));
            *reinterpret_cast<ushort4*>(&Mb[((size_t)b * 64 + v) * 320 + lane * 4]) = u;
        }
    }
}

// ================= D2/D4: update, all-degrees + select =================
// Block = (batch, col-half): 64 rows x 128 cols. 4 waves, wave = 64r x 32c.
// A: LDS XOR-swizzled; B: fragment-ordered global (coalesced, L2-hot).
__global__ __launch_bounds__(256) void k_update(
        const unsigned short* __restrict__ Mb,
        const unsigned short* __restrict__ Wtf,
        const int* __restrict__ degidx,
        unsigned short* __restrict__ hout) {
    __shared__ __align__(16) unsigned short As[64 * 320];   // 40 KB
    __shared__ __align__(16) unsigned short Ct[64 * 128];   // 16 KB
    __shared__ int degs[64];
    const int bid = blockIdx.x;
    const int b = bid >> 1, half = bid & 1;
    const int tid = threadIdx.x;
    {   // stage A (coalesced) with XOR swizzle: chunk ^= row&7
        const char* src = reinterpret_cast<const char*>(Mb + (size_t)b * 64 * 320);
        #pragma unroll
        for (int j = 0; j < 10; ++j) {
            int l = j * 4096 + tid * 16;
            int row = l / 640;
            int wb = l - row * 640;
            uint4 v = *reinterpret_cast<const uint4*>(src + l);
            *reinterpret_cast<uint4*>(
                reinterpret_cast<char*>(As) + row * 640 + (wb ^ ((row & 7) << 4))) = v;
        }
        if (tid < 64) degs[tid] = degidx[b * 64 + tid];
        uint4 z = make_uint4(0, 0, 0, 0);
        #pragma unroll
        for (int j = 0; j < 4; ++j)   // FIX(R5->R6): 32 ushorts/thread, 256*32 = 8192 = |Ct|
            *reinterpret_cast<uint4*>(&Ct[tid * 32 + j * 8]) = z;
    }
    __syncthreads();
    const int w = tid >> 6, lane = tid & 63, gq = lane >> 4, c16 = lane & 15;
    const int cb0 = half * 8 + w * 2;
    const int swz = (c16 & 7) << 4;
    int dg[4][4];
    #pragma unroll
    for (int rt = 0; rt < 4; ++rt)
        #pragma unroll
        for (int jj = 0; jj < 4; ++jj)
            dg[rt][jj] = degs[rt * 16 + gq * 4 + jj];
    for (int d = 0; d < ND; ++d) {
        f32x4 acc[4][2];
        #pragma unroll
        for (int rt = 0; rt < 4; ++rt) {
            acc[rt][0] = (f32x4){0.f, 0.f, 0.f, 0.f};
            acc[rt][1] = (f32x4){0.f, 0.f, 0.f, 0.f};
        }
        #pragma unroll
        for (int ks = 0; ks < 10; ++ks) {
            s16x8 af[4], bf[2];
            #pragma unroll
            for (int rt = 0; rt < 4; ++rt)
                af[rt] = *reinterpret_cast<const s16x8*>(
                    reinterpret_cast<const char*>(As) + (rt * 16 + c16) * 640 +
                    ((ks * 64 + gq * 16) ^ swz));
            #pragma unroll
            for (int ct = 0; ct < 2; ++ct)
                bf[ct] = *reinterpret_cast<const s16x8*>(
                    &Wtf[((((size_t)d * 16 + cb0 + ct) * 10 + ks) * 64 + lane) * 8]);
            #pragma unroll
            for (int rt = 0; rt < 4; ++rt) {
                acc[rt][0] = __builtin_amdgcn_mfma_f32_16x16x32_bf16(af[rt], bf[0], acc[rt][0], 0, 0, 0);
                acc[rt][1] = __builtin_amdgcn_mfma_f32_16x16x32_bf16(af[rt], bf[1], acc[rt][1], 0, 0, 0);
            }
        }
        #pragma unroll
        for (int rt = 0; rt < 4; ++rt)
            #pragma unroll
            for (int jj = 0; jj < 4; ++jj)
                if (dg[rt][jj] == d) {
                    int row = rt * 16 + gq * 4 + jj;
                    Ct[row * 128 + w * 32 + c16]      = f2bf(sig1(acc[rt][0][jj]));
                    Ct[row * 128 + w * 32 + 16 + c16] = f2bf(sig1(acc[rt][1][jj]));
                }
    }
    __syncthreads();
    {   // contiguous coalesced row writes
        const int row = tid >> 2, seg = tid & 3;
        unsigned short* dst = hout + ((size_t)(b * 64 + row)) * 256 + half * 128;
        #pragma unroll
        for (int j = 0; j < 4; ++j)
            *reinterpret_cast<uint4*>(&dst[seg * 32 + j * 8]) =
                *reinterpret_cast<const uint4*>(&Ct[row * 128 + seg * 32 + j * 8]);
    }
}

// ================= D3: sparse m_h from bf16 h =================
__global__ __launch_bounds__(256) void k_mh_sparse(const float* __restrict__ g,
                                                   const unsigned short* __restrict__ hb,
                                                   unsigned short* __restrict__ Mb) {
    __shared__ __align__(16) unsigned short hs[NN * 256];   // 32 KB
    const int b = blockIdx.x;
    const int tid = threadIdx.x;
    {
        const uint4* src = reinterpret_cast<const uint4*>(hb) + (size_t)b * 2048;
        uint4* dst = reinterpret_cast<uint4*>(hs);
        #pragma unroll
        for (int j = 0; j < 8; ++j) dst[j * 256 + tid] = src[j * 256 + tid];
    }
    __syncthreads();
    const int wv = tid >> 6, lane = tid & 63;
    for (int s = 0; s < 16; ++s) {
        const int v = wv * 16 + s;
        float gval = g[((size_t)b * 64 + v) * 64 + lane];
        unsigned long long mask = __ballot(gval != 0.f);
        if (__popcll(mask) > 10) continue;
        float4 acc = make_float4(0.f, 0.f, 0.f, 0.f);
        while (mask) {
            int w = __builtin_ctzll(mask); mask &= mask - 1;
            ushort4 hv = *reinterpret_cast<const ushort4*>(&hs[w * 256 + lane * 4]);
            acc.x += bf2f(hv.x); acc.y += bf2f(hv.y);
            acc.z += bf2f(hv.z); acc.w += bf2f(hv.w);
        }
        ushort4 u = make_ushort4(f2bf(acc.x), f2bf(acc.y), f2bf(acc.z), f2bf(acc.w));
        *reinterpret_cast<ushort4*>(&Mb[((size_t)b * 64 + v) * 320 + lane * 4]) = u;
    }
}

// ================= D5: readout (3 layers, LDS-staged A + frag B) + MLP =================
__global__ __launch_bounds__(256) void k_readout_mlp(
        const unsigned short* __restrict__ hb0,
        const unsigned short* __restrict__ hb1,
        const unsigned short* __restrict__ hb2,
        const unsigned short* __restrict__ Rtf,
        const int* __restrict__ degidx,
        const float* __restrict__ fc0w, const float* __restrict__ fc0b,
        const float* __restrict__ fc1w, const float* __restrict__ fc1b,
        const float* __restrict__ fc2w, const float* __restrict__ fc2b,
        const float* __restrict__ fc3w, const float* __restrict__ fc3b,
        float* __restrict__ out) {
    const int b = blockIdx.x;
    const int tid = threadIdx.x;
    const int w = tid >> 6, lane = tid & 63, gq = lane >> 4, c16 = lane & 15;
    __shared__ __align__(16) unsigned short Ah[64 * 256];   // 32 KB swizzled
    __shared__ float x0[512];
    __shared__ float red2[4][64];
    __shared__ __align__(16) float red3[64];
    __shared__ float flags[64];
    __shared__ float part[256];
    __shared__ float x1[128], x2[256], x3[128];
    if (tid < 64) flags[tid] = (degidx[b * 64 + tid] >= 0) ? 1.f : 0.f;
    x0[tid] = 0.f; x0[tid + 256] = 0.f;
    const int swz = (c16 & 7) << 4;

    for (int layer = 0; layer < 3; ++layer) {
        const unsigned short* hb = (layer == 0) ? hb0 : ((layer == 1) ? hb1 : hb2);
        {   // stage A tile, XOR-swizzled
            const char* src = reinterpret_cast<const char*>(hb + (size_t)b * 64 * 256);
            #pragma unroll
            for (int j = 0; j < 8; ++j) {
                int l = j * 4096 + tid * 16;
                int row = l >> 9;
                int wb = l & 511;
                uint4 v = *reinterpret_cast<const uint4*>(src + l);
                *reinterpret_cast<uint4*>(
                    reinterpret_cast<char*>(Ah) + row * 512 + (wb ^ ((row & 7) << 4))) = v;
            }
        }
        __syncthreads();
        f32x4 acc[4][8];
        #pragma unroll
        for (int rt = 0; rt < 4; ++rt)
            #pragma unroll
            for (int ct = 0; ct < 8; ++ct) acc[rt][ct] = (f32x4){0.f, 0.f, 0.f, 0.f};
        #pragma unroll
        for (int ks = 0; ks < 8; ++ks) {
            s16x8 af[4], bf[8];
            #pragma unroll
            for (int rt = 0; rt < 4; ++rt)
                af[rt] = *reinterpret_cast<const s16x8*>(
                    reinterpret_cast<const char*>(Ah) + (rt * 16 + c16) * 512 +
                    ((ks * 64 + gq * 16) ^ swz));
            #pragma unroll
            for (int ct = 0; ct < 8; ++ct)
                bf[ct] = *reinterpret_cast<const s16x8*>(
                    &Rtf[((((size_t)layer * 32 + w * 8 + ct) * 8 + ks) * 64 + lane) * 8]);
            #pragma unroll
            for (int rt = 0; rt < 4; ++rt)
                #pragma unroll
                for (int ct = 0; ct < 8; ++ct)
                    acc[rt][ct] = __builtin_amdgcn_mfma_f32_16x16x32_bf16(af[rt], bf[ct], acc[rt][ct], 0, 0, 0);
        }
        // exp in place; per-row sums over this wave's 128 cols
        float rs[4][4];
        #pragma unroll
        for (int rt = 0; rt < 4; ++rt) {
            #pragma unroll
            for (int j = 0; j < 4; ++j) rs[rt][j] = 0.f;
            #pragma unroll
            for (int ct = 0; ct < 8; ++ct) {
                #pragma unroll
                for (int j = 0; j < 4; ++j) {
                    float p = __expf(acc[rt][ct][j]);
                    acc[rt][ct][j] = p;
                    rs[rt][j] += p;
                }
            }
        }
        #pragma unroll
        for (int rt = 0; rt < 4; ++rt)
            #pragma unroll
            for (int j = 0; j < 4; ++j) {
                float s = rs[rt][j];
                #pragma unroll
                for (int m = 1; m <= 8; m <<= 1) s += __shfl_xor(s, m);
                rs[rt][j] = s;
            }
        if (c16 == 0) {
            #pragma unroll
            for (int rt = 0; rt < 4; ++rt)
                #pragma unroll
                for (int j = 0; j < 4; ++j)
                    red2[w][rt * 16 + gq * 4 + j] = rs[rt][j];
        }
        __syncthreads();
        if (tid < 64) {
            float s = red2[0][tid] + red2[1][tid] + red2[2][tid] + red2[3][tid];
            red3[tid] = ((layer == 0) ? 1.f : flags[tid]) / s;
        }
        __syncthreads();
        f32x4 iv[4];
        #pragma unroll
        for (int rt = 0; rt < 4; ++rt)
            iv[rt] = *reinterpret_cast<const f32x4*>(&red3[rt * 16 + gq * 4]);
        #pragma unroll
        for (int ct = 0; ct < 8; ++ct) {
            f32x4 t = (f32x4){0.f, 0.f, 0.f, 0.f};
            #pragma unroll
            for (int rt = 0; rt < 4; ++rt) t += acc[rt][ct] * iv[rt];
            float v = t[0] + t[1] + t[2] + t[3];
            v += __shfl_xor(v, 16);
            v += __shfl_xor(v, 32);
            if (lane < 16) x0[w * 128 + ct * 16 + lane] += v;
        }
        __syncthreads();
    }
    // ---- MLP on x0[512] ----
    {
        const int o = tid & 127, half = tid >> 7;
        float a = 0.f;
        const int i0 = half * 256;
        for (int i = 0; i < 256; ++i) a = fmaf(x0[i0 + i], fc0w[(size_t)(i0 + i) * 128 + o], a);
        part[tid] = a;
    }
    __syncthreads();
    if (tid < 128) x1[tid] = fmaxf(fc0b[tid] + part[tid] + part[tid + 128], 0.f);
    __syncthreads();
    {
        float a = fc1b[tid];
        for (int i = 0; i < 128; ++i) a = fmaf(x1[i], fc1w[(size_t)i * 256 + tid], a);
        x2[tid] = fmaxf(a, 0.f);
    }
    __syncthreads();
    {
        const int o = tid & 127, half = tid >> 7;
        float a = 0.f;
        const int i0 = half * 128;
        for (int i = 0; i < 128; ++i) a = fmaf(x2[i0 + i], fc2w[(size_t)(i0 + i) * 128 + o], a);
        part[tid] = a;
    }
    __syncthreads();
    if (tid < 128) x3[tid] = fmaxf(fc2b[tid] + part[tid] + part[tid + 128], 0.f);
    __syncthreads();
    if (tid < TGT) {
        float a = fc3b[tid];
        for (int i = 0; i < 128; ++i) a = fmaf(x3[i], fc3w[(size_t)i * TGT + tid], a);
        out[(size_t)b * TGT + tid] = a;
    }
}

extern "C" void kernel_launch(void* const* d_in, const int* in_sizes, int n_in,
                              void* d_out, int out_size, void* d_ws, size_t ws_size,
                              hipStream_t stream) {
    (void)in_sizes; (void)n_in; (void)out_size; (void)ws_size;
    const float* g    = (const float*)d_in[0];
    const float* h_in = (const float*)d_in[1];
    const float* e    = (const float*)d_in[2];
    const float* Wu0  = (const float*)d_in[3];
    const float* Wu1  = (const float*)d_in[4];
    const float* R    = (const float*)d_in[5];
    const float* fc0w = (const float*)d_in[6];
    const float* fc0b = (const float*)d_in[7];
    const float* fc1w = (const float*)d_in[8];
    const float* fc1b = (const float*)d_in[9];
    const float* fc2w = (const float*)d_in[10];
    const float* fc2b = (const float*)d_in[11];
    const float* fc3w = (const float*)d_in[12];
    const float* fc3b = (const float*)d_in[13];
    float* out = (float*)d_out;

    char* p = (char*)d_ws;
    unsigned short* Mb   = (unsigned short*)p; p += (size_t)NNODES * 320 * 2;     // 10 MB
    unsigned short* hb0  = (unsigned short*)p; p += (size_t)NNODES * 256 * 2;     // 8 MB
    unsigned short* hb1  = (unsigned short*)p; p += (size_t)NNODES * 256 * 2;     // 8 MB
    unsigned short* hb2  = (unsigned short*)p; p += (size_t)NNODES * 256 * 2;     // 8 MB
    unsigned short* Rtf  = (unsigned short*)p; p += (size_t)3 * 32 * 8 * 512 * 2;   // 0.75 MB
    unsigned short* Wtf0 = (unsigned short*)p; p += (size_t)ND * 16 * 10 * 512 * 2; // 1.76 MB
    unsigned short* Wtf1 = (unsigned short*)p; p += (size_t)ND * 16 * 10 * 512 * 2; // 1.76 MB
    int* degidx = (int*)p;                     p += (size_t)NNODES * 4;           // 64 KB

    k_prep<<<NB_TOTAL, 256, 0, stream>>>(g, e, h_in, R, Wu0, Wu1,
                                         Mb, hb0, Rtf, Wtf0, Wtf1, degidx);
    k_update<<<2 * BB, 256, 0, stream>>>(Mb, Wtf0, degidx, hb1);
    k_mh_sparse<<<BB, 256, 0, stream>>>(g, hb1, Mb);
    k_update<<<2 * BB, 256, 0, stream>>>(Mb, Wtf1, degidx, hb2);
    k_readout_mlp<<<BB, 256, 0, stream>>>(hb0, hb1, hb2, Rtf, degidx,
                                          fc0w, fc0b, fc1w, fc1b, fc2w, fc2b, fc3w, fc3b, out);
}